// Round 3
// baseline (872.794 us; speedup 1.0000x reference)
//
#include <hip/hip_runtime.h>

// QNetGNN: 2-layer GCN, N=100000, E=3.2M, F: 128 -> 16 -> 32.
// R3: two-level bucketing. Edges binned into 782 coarse buckets (128 dst nodes
// each) with LDS counting-sort per tile -> coalesced run writes (4B packed
// entries: src<<7 | dloc). Aggregation: one block per bucket, LDS fp32
// accumulator (stride 17 anti-bank-conflict), LDS atomics. Degrees derived
// per-bucket (no global histogram atomics). Epilogues fused (bias/relu; W2
// matmul). No fine CSR, no global float atomics.

#define NNODES 100000
#define FIN    128
#define FHID   16
#define NACT   32
#define NB     782          // ceil(100000/128) buckets of 128 dst nodes
#define TILE   8192

// ---- coarse histogram of dst buckets ----
__global__ void k_coarse(const int* __restrict__ dst, int E, int* __restrict__ bcnt) {
    __shared__ int hist[NB];
    int t = threadIdx.x;
    int tb = blockIdx.x * TILE;
    int tn = min(TILE, E - tb);
    for (int i = t; i < NB; i += 256) hist[i] = 0;
    __syncthreads();
    for (int i = t; i < tn; i += 256) atomicAdd(&hist[dst[tb + i] >> 7], 1);
    __syncthreads();
    for (int i = t; i < NB; i += 256) if (hist[i]) atomicAdd(&bcnt[i], hist[i]);
}

// ---- exclusive scan of bcnt -> bptr[0..NB], init gcur ----
__global__ void k_scan(const int* __restrict__ bcnt, int* __restrict__ bptr,
                       int* __restrict__ gcur) {
    __shared__ int part[256];
    int t = threadIdx.x;
    int l[4];
    int s = 0;
#pragma unroll
    for (int k = 0; k < 4; ++k) {
        int idx = t * 4 + k;
        l[k] = s;
        s += (idx < NB) ? bcnt[idx] : 0;
    }
    part[t] = s;
    __syncthreads();
    for (int d = 1; d < 256; d <<= 1) {
        int v = part[t];
        int add = (t >= d) ? part[t - d] : 0;
        __syncthreads();
        part[t] = v + add;
        __syncthreads();
    }
    int excl = t ? part[t - 1] : 0;
#pragma unroll
    for (int k = 0; k < 4; ++k) {
        int idx = t * 4 + k;
        if (idx < NB) { bptr[idx] = excl + l[k]; gcur[idx] = excl + l[k]; }
    }
    if (t == 255) bptr[NB] = part[255];
}

// ---- bin: tile-local counting sort by bucket, coalesced run writes ----
__global__ void k_bin(const int* __restrict__ src, const int* __restrict__ dst, int E,
                      int* __restrict__ gcur, unsigned* __restrict__ binned) {
    __shared__ unsigned staged[TILE];     // 32 KB
    __shared__ int hist[NB];
    __shared__ int lstart[NB + 1];
    __shared__ int lcur[NB];
    __shared__ int gbase[NB];
    __shared__ int part[256];
    int t = threadIdx.x;
    int tb = blockIdx.x * TILE;
    int tn = min(TILE, E - tb);
    for (int i = t; i < NB; i += 256) hist[i] = 0;
    __syncthreads();
    for (int i = t; i < tn; i += 256) atomicAdd(&hist[dst[tb + i] >> 7], 1);
    __syncthreads();
    // scan hist -> lstart (exclusive), copy to lcur
    int l[4];
    int s = 0;
#pragma unroll
    for (int k = 0; k < 4; ++k) {
        int idx = t * 4 + k;
        l[k] = s;
        s += (idx < NB) ? hist[idx] : 0;
    }
    part[t] = s;
    __syncthreads();
    for (int d = 1; d < 256; d <<= 1) {
        int v = part[t];
        int add = (t >= d) ? part[t - d] : 0;
        __syncthreads();
        part[t] = v + add;
        __syncthreads();
    }
    int excl = t ? part[t - 1] : 0;
#pragma unroll
    for (int k = 0; k < 4; ++k) {
        int idx = t * 4 + k;
        if (idx < NB) { int st = excl + l[k]; lstart[idx] = st; lcur[idx] = st; }
    }
    if (t == 255) lstart[NB] = part[255];
    __syncthreads();
    // reserve global runs (one atomic per non-empty bucket per tile)
    for (int i = t; i < NB; i += 256) {
        int c = lstart[i + 1] - lstart[i];
        gbase[i] = (c > 0) ? atomicAdd(&gcur[i], c) : 0;
    }
    // local scatter into staged (bucket-ordered)
    for (int i = t; i < tn; i += 256) {
        int d = dst[tb + i], sv = src[tb + i];
        int b = d >> 7;
        int pos = atomicAdd(&lcur[b], 1);
        staged[pos] = ((unsigned)sv << 7) | (unsigned)(d & 127);
    }
    __syncthreads();
    // coalesced write-out: consecutive j -> consecutive global positions
    for (int j = t; j < tn; j += 256) {
        int lo = 0, hi = NB - 1;
        while (lo < hi) {                  // largest b with lstart[b] <= j
            int mid = (lo + hi + 1) >> 1;
            if (lstart[mid] <= j) lo = mid; else hi = mid - 1;
        }
        binned[gbase[lo] + (j - lstart[lo])] = staged[j];
    }
}

// ---- per-bucket degree + dis = rsqrt(deg+1) ----
__global__ void k_deg_dis(const int* __restrict__ bptr, const unsigned* __restrict__ binned,
                          float* __restrict__ dis, int n) {
    __shared__ int cnt[128];
    int t = threadIdx.x;
    int bk = blockIdx.x;
    if (t < 128) cnt[t] = 0;
    __syncthreads();
    int beg = bptr[bk], end = bptr[bk + 1];
    for (int i = beg + t; i < end; i += 256) atomicAdd(&cnt[binned[i] & 127], 1);
    __syncthreads();
    int node = (bk << 7) + t;
    if (t < 128 && node < n) dis[node] = rsqrtf((float)cnt[t] + 1.0f);
}

// ---- h = x @ W1   [N,128]@[128,16] -> [N,16] ----
__global__ void k_xw1(const float* __restrict__ x, const float* __restrict__ W1,
                      float* __restrict__ h, int n) {
    __shared__ float w[FIN * FHID];   // 8 KB
    for (int i = threadIdx.x; i < FIN * FHID; i += blockDim.x) w[i] = W1[i];
    __syncthreads();
    int r = blockIdx.x * blockDim.x + threadIdx.x;
    if (r >= n) return;
    const float4* xr = (const float4*)(x + (long long)r * FIN);
    float acc[FHID];
#pragma unroll
    for (int c = 0; c < FHID; ++c) acc[c] = 0.f;
#pragma unroll 4
    for (int k4 = 0; k4 < FIN / 4; ++k4) {
        float4 xv = xr[k4];
        int k = k4 * 4;
#pragma unroll
        for (int c = 0; c < FHID; ++c) {
            acc[c] += xv.x * w[(k + 0) * FHID + c] + xv.y * w[(k + 1) * FHID + c]
                    + xv.z * w[(k + 2) * FHID + c] + xv.w * w[(k + 3) * FHID + c];
        }
    }
    float4* hr = (float4*)(h + (long long)r * FHID);
    hr[0] = make_float4(acc[0], acc[1], acc[2], acc[3]);
    hr[1] = make_float4(acc[4], acc[5], acc[6], acc[7]);
    hr[2] = make_float4(acc[8], acc[9], acc[10], acc[11]);
    hr[3] = make_float4(acc[12], acc[13], acc[14], acc[15]);
}

// ---- gather: one block per bucket, LDS accumulator, fused epilogue ----
// L==1: outp = relu(di*sum + di^2*feat_self + bias)            [N,16]
// L==2: outp = (di*sum + di^2*feat_self) @ W2 + bias           [N,32]
template <int L>
__global__ void k_gather(const int* __restrict__ bptr, const unsigned* __restrict__ binned,
                         const float* __restrict__ dis, const float* __restrict__ feat,
                         const float* __restrict__ W2, const float* __restrict__ bias,
                         float* __restrict__ outp, int n) {
    __shared__ float acc[128 * 17];   // stride 17: random dloc -> all 32 banks
    __shared__ float wb[FHID * NACT];
    __shared__ float bs[NACT];
    int t = threadIdx.x;
    int bk = blockIdx.x;
    int base = bk << 7;
    for (int i = t; i < 128 * 17; i += 256) acc[i] = 0.f;
    if (L == 2) {
        for (int i = t; i < FHID * NACT; i += 256) wb[i] = W2[i];
        if (t < NACT) bs[t] = bias[t];
    } else {
        if (t < FHID) bs[t] = bias[t];
    }
    __syncthreads();
    int beg = bptr[bk], end = bptr[bk + 1];
    int p = t & 3;
    for (int i = beg + (t >> 2); i < end; i += 64) {
        unsigned e = binned[i];
        int s = e >> 7;
        int dloc = e & 127;
        float w = dis[s];
        float4 v = ((const float4*)feat)[(size_t)s * 4 + p];
        float* a = &acc[dloc * 17 + p * 4];
        atomicAdd(a + 0, v.x * w);
        atomicAdd(a + 1, v.y * w);
        atomicAdd(a + 2, v.z * w);
        atomicAdd(a + 3, v.w * w);
    }
    __syncthreads();
    int j = t >> 1, half = t & 1;
    int node = base + j;
    if (node < n) {
        float di = dis[node], sw = di * di;
        if (L == 1) {
#pragma unroll
            for (int q = 0; q < 2; ++q) {
                int c = half * 8 + q * 4;
                float4 hv = ((const float4*)feat)[(size_t)node * 4 + (c >> 2)];
                float4 r;
                r.x = fmaxf(di * acc[j * 17 + c + 0] + sw * hv.x + bs[c + 0], 0.f);
                r.y = fmaxf(di * acc[j * 17 + c + 1] + sw * hv.y + bs[c + 1], 0.f);
                r.z = fmaxf(di * acc[j * 17 + c + 2] + sw * hv.z + bs[c + 2], 0.f);
                r.w = fmaxf(di * acc[j * 17 + c + 3] + sw * hv.w + bs[c + 3], 0.f);
                ((float4*)outp)[(size_t)node * 4 + (c >> 2)] = r;
            }
        } else {
            float v[FHID];
#pragma unroll
            for (int q = 0; q < 4; ++q) {
                float4 hv = ((const float4*)feat)[(size_t)node * 4 + q];
                v[q * 4 + 0] = di * acc[j * 17 + q * 4 + 0] + sw * hv.x;
                v[q * 4 + 1] = di * acc[j * 17 + q * 4 + 1] + sw * hv.y;
                v[q * 4 + 2] = di * acc[j * 17 + q * 4 + 2] + sw * hv.z;
                v[q * 4 + 3] = di * acc[j * 17 + q * 4 + 3] + sw * hv.w;
            }
            float o[16];
#pragma unroll
            for (int oo = 0; oo < 16; ++oo) {
                int col = half * 16 + oo;
                float a = bs[col];
#pragma unroll
                for (int c = 0; c < FHID; ++c) a += v[c] * wb[c * NACT + col];
                o[oo] = a;
            }
#pragma unroll
            for (int q = 0; q < 4; ++q)
                ((float4*)outp)[(size_t)node * 8 + half * 4 + q] =
                    make_float4(o[q * 4], o[q * 4 + 1], o[q * 4 + 2], o[q * 4 + 3]);
        }
    }
}

extern "C" void kernel_launch(void* const* d_in, const int* in_sizes, int n_in,
                              void* d_out, int out_size, void* d_ws, size_t ws_size,
                              hipStream_t stream) {
    const float* x  = (const float*)d_in[0];
    const float* W1 = (const float*)d_in[1];
    const float* b1 = (const float*)d_in[2];
    const float* W2 = (const float*)d_in[3];
    const float* b2 = (const float*)d_in[4];
    const int*   ei = (const int*)d_in[5];
    const int E = in_sizes[5] / 2;
    const int n = NNODES;
    const int* src = ei;
    const int* dst = ei + E;

    // workspace: floats dis[n] h[16n] h1[16n], then ints bcnt[NB] bptr[NB+1]
    // gcur[NB] binned[E]
    float* fb  = (float*)d_ws;
    float* dis = fb;
    float* h   = fb + (size_t)n;
    float* h1  = fb + (size_t)17 * n;
    int* ib    = (int*)(fb + (size_t)33 * n);
    int* bcnt  = ib;
    int* bptr  = ib + NB;
    int* gcur  = ib + 2 * NB + 1;
    unsigned* binned = (unsigned*)(ib + 3 * NB + 1);

    hipMemsetAsync(bcnt, 0, NB * sizeof(int), stream);

    const int B = 256;
    int ntiles = (E + TILE - 1) / TILE;
    k_coarse<<<ntiles, B, 0, stream>>>(dst, E, bcnt);
    k_scan<<<1, B, 0, stream>>>(bcnt, bptr, gcur);
    k_bin<<<ntiles, B, 0, stream>>>(src, dst, E, gcur, binned);
    k_deg_dis<<<NB, B, 0, stream>>>(bptr, binned, dis, n);
    k_xw1<<<(n + B - 1) / B, B, 0, stream>>>(x, W1, h, n);
    k_gather<1><<<NB, B, 0, stream>>>(bptr, binned, dis, h, nullptr, b1, h1, n);
    k_gather<2><<<NB, B, 0, stream>>>(bptr, binned, dis, h1, W2, b2, (float*)d_out, n);
}

// Round 5
// 310.101 us; speedup vs baseline: 2.8145x; 2.8145x over previous
//
#include <hip/hip_runtime.h>

// QNetGNN: 2-layer GCN, N=100000, E=3.2M, F: 128 -> 16 -> 32.
// R5 (= R4 + compile fix): bucket counting-sort (coalesced) -> node-ordered
// padded CSR; per-node quad gather with 4-edge int4 batches (4 independent
// float4 loads in flight) over PRE-SCALED features (featp = h*dis).
// Self loop = add own pre-scaled row. Dummy row n is all-zero for padding.

#define NNODES 100000
#define FIN    128
#define FHID   16
#define NACT   32
#define NB     782          // ceil(100000/128) buckets of 128 dst nodes
#define TILE   8192

__global__ void k_coarse(const int* __restrict__ dst, int E, int* __restrict__ bcnt) {
    __shared__ int hist[NB];
    int t = threadIdx.x;
    int tb = blockIdx.x * TILE;
    int tn = min(TILE, E - tb);
    for (int i = t; i < NB; i += 256) hist[i] = 0;
    __syncthreads();
    for (int i = t; i < tn; i += 256) atomicAdd(&hist[dst[tb + i] >> 7], 1);
    __syncthreads();
    for (int i = t; i < NB; i += 256) if (hist[i]) atomicAdd(&bcnt[i], hist[i]);
}

__global__ void k_scan(const int* __restrict__ bcnt, int* __restrict__ bptr,
                       int* __restrict__ gcur) {
    __shared__ int part[256];
    int t = threadIdx.x;
    int l[4];
    int s = 0;
#pragma unroll
    for (int k = 0; k < 4; ++k) {
        int idx = t * 4 + k;
        l[k] = s;
        s += (idx < NB) ? bcnt[idx] : 0;
    }
    part[t] = s;
    __syncthreads();
    for (int d = 1; d < 256; d <<= 1) {
        int v = part[t];
        int add = (t >= d) ? part[t - d] : 0;
        __syncthreads();
        part[t] = v + add;
        __syncthreads();
    }
    int excl = t ? part[t - 1] : 0;
#pragma unroll
    for (int k = 0; k < 4; ++k) {
        int idx = t * 4 + k;
        if (idx < NB) { bptr[idx] = excl + l[k]; gcur[idx] = excl + l[k]; }
    }
    if (t == 255) bptr[NB] = part[255];
}

__global__ void k_bin(const int* __restrict__ src, const int* __restrict__ dst, int E,
                      int* __restrict__ gcur, unsigned* __restrict__ binned) {
    __shared__ unsigned staged[TILE];     // 32 KB
    __shared__ int hist[NB];
    __shared__ int lstart[NB + 1];
    __shared__ int lcur[NB];
    __shared__ int gbase[NB];
    __shared__ int part[256];
    int t = threadIdx.x;
    int tb = blockIdx.x * TILE;
    int tn = min(TILE, E - tb);
    for (int i = t; i < NB; i += 256) hist[i] = 0;
    __syncthreads();
    for (int i = t; i < tn; i += 256) atomicAdd(&hist[dst[tb + i] >> 7], 1);
    __syncthreads();
    int l[4];
    int s = 0;
#pragma unroll
    for (int k = 0; k < 4; ++k) {
        int idx = t * 4 + k;
        l[k] = s;
        s += (idx < NB) ? hist[idx] : 0;
    }
    part[t] = s;
    __syncthreads();
    for (int d = 1; d < 256; d <<= 1) {
        int v = part[t];
        int add = (t >= d) ? part[t - d] : 0;
        __syncthreads();
        part[t] = v + add;
        __syncthreads();
    }
    int excl = t ? part[t - 1] : 0;
#pragma unroll
    for (int k = 0; k < 4; ++k) {
        int idx = t * 4 + k;
        if (idx < NB) { int st = excl + l[k]; lstart[idx] = st; lcur[idx] = st; }
    }
    if (t == 255) lstart[NB] = part[255];
    __syncthreads();
    for (int i = t; i < NB; i += 256) {
        int c = lstart[i + 1] - lstart[i];
        gbase[i] = (c > 0) ? atomicAdd(&gcur[i], c) : 0;
    }
    for (int i = t; i < tn; i += 256) {
        int d = dst[tb + i], sv = src[tb + i];
        int b = d >> 7;
        int pos = atomicAdd(&lcur[b], 1);
        staged[pos] = ((unsigned)sv << 7) | (unsigned)(d & 127);
    }
    __syncthreads();
    for (int j = t; j < tn; j += 256) {
        int lo = 0, hi = NB - 1;
        while (lo < hi) {
            int mid = (lo + hi + 1) >> 1;
            if (lstart[mid] <= j) lo = mid; else hi = mid - 1;
        }
        binned[gbase[lo] + (j - lstart[lo])] = staged[j];
    }
}

// ---- per-bucket: degrees -> dis; padded node-ordered CSR scatter ----
__global__ void k_csr(const int* __restrict__ bptr, const unsigned* __restrict__ binned,
                      float* __restrict__ dis, int* __restrict__ rowptr,
                      int* __restrict__ plen4, int* __restrict__ csr, int n) {
    __shared__ int cnt[128];
    __shared__ int pl[128];
    __shared__ int part[128];
    __shared__ int lbase[128];
    __shared__ int lcur[128];
    int t = threadIdx.x;
    int bk = blockIdx.x;
    int beg = bptr[bk], end = bptr[bk + 1];
    int rbase = (beg & ~3) + 512 * bk;    // 16B-aligned, padding headroom
    if (t < 128) cnt[t] = 0;
    __syncthreads();
    for (int i = beg + t; i < end; i += 256) atomicAdd(&cnt[binned[i] & 127], 1);
    __syncthreads();
    if (t < 128) { pl[t] = (cnt[t] + 3) & ~3; part[t] = pl[t]; }
    __syncthreads();
    for (int d = 1; d < 128; d <<= 1) {
        int v = 0;
        if (t < 128) { v = part[t]; if (t >= d) v += part[t - d]; }
        __syncthreads();
        if (t < 128) part[t] = v;
        __syncthreads();
    }
    if (t < 128) {
        lbase[t] = t ? part[t - 1] : 0;
        lcur[t] = 0;
        int node = (bk << 7) + t;
        if (node < n) {
            int rp = rbase + lbase[t];
            rowptr[node] = rp;
            plen4[node] = pl[t] >> 2;
            dis[node] = rsqrtf((float)cnt[t] + 1.0f);
            for (int k = cnt[t]; k < pl[t]; ++k) csr[rp + k] = n;  // dummy pad
        }
    }
    __syncthreads();
    for (int i = beg + t; i < end; i += 256) {
        unsigned e = binned[i];
        int dloc = e & 127;
        int pos = atomicAdd(&lcur[dloc], 1);
        csr[rbase + lbase[dloc] + pos] = (int)(e >> 7);
    }
}

// ---- featp = (x @ W1) * dis; row n = zeros ----
__global__ void k_xw1(const float* __restrict__ x, const float* __restrict__ W1,
                      const float* __restrict__ dis, float* __restrict__ featp, int n) {
    __shared__ float w[FIN * FHID];   // 8 KB
    for (int i = threadIdx.x; i < FIN * FHID; i += blockDim.x) w[i] = W1[i];
    __syncthreads();
    int r = blockIdx.x * blockDim.x + threadIdx.x;
    if (r > n) return;
    float4* hr = (float4*)(featp + (long long)r * FHID);
    if (r == n) {
        float4 z = make_float4(0.f, 0.f, 0.f, 0.f);
        hr[0] = z; hr[1] = z; hr[2] = z; hr[3] = z;
        return;
    }
    const float4* xr = (const float4*)(x + (long long)r * FIN);
    float acc[FHID];
#pragma unroll
    for (int c = 0; c < FHID; ++c) acc[c] = 0.f;
#pragma unroll 4
    for (int k4 = 0; k4 < FIN / 4; ++k4) {
        float4 xv = xr[k4];
        int k = k4 * 4;
#pragma unroll
        for (int c = 0; c < FHID; ++c) {
            acc[c] += xv.x * w[(k + 0) * FHID + c] + xv.y * w[(k + 1) * FHID + c]
                    + xv.z * w[(k + 2) * FHID + c] + xv.w * w[(k + 3) * FHID + c];
        }
    }
    float d = dis[r];
    hr[0] = make_float4(acc[0] * d, acc[1] * d, acc[2] * d, acc[3] * d);
    hr[1] = make_float4(acc[4] * d, acc[5] * d, acc[6] * d, acc[7] * d);
    hr[2] = make_float4(acc[8] * d, acc[9] * d, acc[10] * d, acc[11] * d);
    hr[3] = make_float4(acc[12] * d, acc[13] * d, acc[14] * d, acc[15] * d);
}

// ---- gather: 4 lanes/node, 4 edges/iter (int4 + 4 independent float4) ----
template <int L>
__global__ void k_gather(const int* __restrict__ rowptr, const int* __restrict__ plen4,
                         const int* __restrict__ csr, const float* __restrict__ dis,
                         const float* __restrict__ featp, const float* __restrict__ bias,
                         float* __restrict__ outp, int n) {
    int t = blockIdx.x * blockDim.x + threadIdx.x;
    int node = t >> 2, p = t & 3;
    if (node > n) return;
    if (node == n) {
        if (L == 1) ((float4*)outp)[(size_t)node * 4 + p] = make_float4(0.f, 0.f, 0.f, 0.f);
        return;
    }
    const float4* fp = (const float4*)featp;
    float4 a = fp[(size_t)node * 4 + p];          // self loop (pre-scaled)
    int beg = rowptr[node];
    int it = plen4[node];
    const int4* cp = (const int4*)(csr + beg);
    for (int k = 0; k < it; ++k) {
        int4 s4 = cp[k];
        float4 v0 = fp[(size_t)s4.x * 4 + p];
        float4 v1 = fp[(size_t)s4.y * 4 + p];
        float4 v2 = fp[(size_t)s4.z * 4 + p];
        float4 v3 = fp[(size_t)s4.w * 4 + p];
        a.x += (v0.x + v1.x) + (v2.x + v3.x);
        a.y += (v0.y + v1.y) + (v2.y + v3.y);
        a.z += (v0.z + v1.z) + (v2.z + v3.z);
        a.w += (v0.w + v1.w) + (v2.w + v3.w);
    }
    float di = dis[node];
    float4 r;
    if (L == 1) {
        float4 bv = ((const float4*)bias)[p];
        r.x = fmaxf(di * a.x + bv.x, 0.f) * di;   // pre-scaled for layer 2
        r.y = fmaxf(di * a.y + bv.y, 0.f) * di;
        r.z = fmaxf(di * a.z + bv.z, 0.f) * di;
        r.w = fmaxf(di * a.w + bv.w, 0.f) * di;
    } else {
        r.x = di * a.x; r.y = di * a.y; r.z = di * a.z; r.w = di * a.w;
    }
    ((float4*)outp)[(size_t)node * 4 + p] = r;
}

// ---- out = v @ W2 + b2 ----
__global__ void k_out(const float* __restrict__ v, const float* __restrict__ W2,
                      const float* __restrict__ b2, float* __restrict__ out, int n) {
    __shared__ float w[FHID * NACT];
    __shared__ float bb[NACT];
    for (int i = threadIdx.x; i < FHID * NACT; i += blockDim.x) w[i] = W2[i];
    if (threadIdx.x < NACT) bb[threadIdx.x] = b2[threadIdx.x];
    __syncthreads();
    int t = blockIdx.x * blockDim.x + threadIdx.x;
    int i = t >> 3, p = t & 7;
    if (i >= n) return;
    float vv[FHID];
    const float4* v4 = (const float4*)(v + (long long)i * FHID);
#pragma unroll
    for (int q = 0; q < 4; ++q) {
        float4 a = v4[q];
        vv[q * 4 + 0] = a.x; vv[q * 4 + 1] = a.y; vv[q * 4 + 2] = a.z; vv[q * 4 + 3] = a.w;
    }
    float acc0 = bb[p * 4 + 0], acc1 = bb[p * 4 + 1], acc2 = bb[p * 4 + 2], acc3 = bb[p * 4 + 3];
#pragma unroll
    for (int c = 0; c < FHID; ++c) {
        float vc = vv[c];
        acc0 += vc * w[c * NACT + p * 4 + 0];
        acc1 += vc * w[c * NACT + p * 4 + 1];
        acc2 += vc * w[c * NACT + p * 4 + 2];
        acc3 += vc * w[c * NACT + p * 4 + 3];
    }
    ((float4*)out)[(long long)i * 8 + p] = make_float4(acc0, acc1, acc2, acc3);
}

extern "C" void kernel_launch(void* const* d_in, const int* in_sizes, int n_in,
                              void* d_out, int out_size, void* d_ws, size_t ws_size,
                              hipStream_t stream) {
    const float* x  = (const float*)d_in[0];
    const float* W1 = (const float*)d_in[1];
    const float* b1 = (const float*)d_in[2];
    const float* W2 = (const float*)d_in[3];
    const float* b2 = (const float*)d_in[4];
    const int*   ei = (const int*)d_in[5];
    const int E = in_sizes[5] / 2;
    const int n = NNODES;
    const int* src = ei;
    const int* dst = ei + E;

    // floats: dis[n] featp[16(n+1)] h1p[16(n+1)] v2[16n]
    // ints:   bcnt[NB] bptr[NB+1] gcur[NB] rowptr[n] plen4[n] | binned[E] | csr[E+512*NB+64]
    float* fb    = (float*)d_ws;
    float* dis   = fb;
    float* featp = fb + (size_t)n;
    float* h1p   = featp + (size_t)16 * (n + 1);
    float* v2    = h1p + (size_t)16 * (n + 1);
    int*   ib    = (int*)(v2 + (size_t)16 * n);
    int*   bcnt  = ib;
    int*   bptr  = ib + NB;
    int*   gcur  = ib + 2 * NB + 1;
    int*   rowptr = ib + 3 * NB + 1;
    int*   plen4 = rowptr + n;
    size_t binned_off = (size_t)(3 * NB + 1) + 2 * (size_t)n;
    unsigned* binned = (unsigned*)(ib + binned_off);
    size_t csr_off = (binned_off + (size_t)E + 3) & ~(size_t)3;  // 16B-align
    int*   csr   = ib + csr_off;

    (void)hipMemsetAsync(bcnt, 0, NB * sizeof(int), stream);

    const int B = 256;
    int ntiles = (E + TILE - 1) / TILE;
    k_coarse<<<ntiles, B, 0, stream>>>(dst, E, bcnt);
    k_scan<<<1, B, 0, stream>>>(bcnt, bptr, gcur);
    k_bin<<<ntiles, B, 0, stream>>>(src, dst, E, gcur, binned);
    k_csr<<<NB, B, 0, stream>>>(bptr, binned, dis, rowptr, plen4, csr, n);
    k_xw1<<<(n + 1 + B - 1) / B, B, 0, stream>>>(x, W1, dis, featp, n);
    k_gather<1><<<((n + 1) * 4 + B - 1) / B, B, 0, stream>>>(rowptr, plen4, csr, dis, featp, b1, h1p, n);
    k_gather<2><<<((n + 1) * 4 + B - 1) / B, B, 0, stream>>>(rowptr, plen4, csr, dis, h1p, nullptr, v2, n);
    k_out<<<(8 * n + B - 1) / B, B, 0, stream>>>(v2, W2, b2, (float*)d_out, n);
}

// Round 6
// 301.376 us; speedup vs baseline: 2.8960x; 1.0289x over previous
//
#include <hip/hip_runtime.h>

// QNetGNN: 2-layer GCN, N=100000, E=3.2M, F: 128 -> 16 -> 32.
// R6: TILE=4096 binning with precomputed scatter destinations (no binary
// search), tile histograms reused from k_coarse (ushort thist), W2 matmul
// fused into gather<2> epilogue via cross-lane shfl. Pre-scaled features
// (featp = h*dis); self loop = own row; dummy row n = zeros for padding.

#define NNODES 100000
#define FIN    128
#define FHID   16
#define NACT   32
#define NB     782          // ceil(100000/128) buckets of 128 dst nodes
#define TILE   4096

// ---- coarse histogram of dst buckets; also store per-tile hist (ushort) ----
__global__ void k_coarse(const int* __restrict__ dst, int E, int* __restrict__ bcnt,
                         unsigned short* __restrict__ thist) {
    __shared__ int hist[NB];
    int t = threadIdx.x;
    int tb = blockIdx.x * TILE;
    int tn = min(TILE, E - tb);
    for (int i = t; i < NB; i += 256) hist[i] = 0;
    __syncthreads();
    for (int i = t; i < tn; i += 256) atomicAdd(&hist[dst[tb + i] >> 7], 1);
    __syncthreads();
    size_t row = (size_t)blockIdx.x * NB;
    for (int i = t; i < NB; i += 256) {
        int hv = hist[i];
        thist[row + i] = (unsigned short)hv;
        if (hv) atomicAdd(&bcnt[i], hv);
    }
}

__global__ void k_scan(const int* __restrict__ bcnt, int* __restrict__ bptr,
                       int* __restrict__ gcur) {
    __shared__ int part[256];
    int t = threadIdx.x;
    int l[4];
    int s = 0;
#pragma unroll
    for (int k = 0; k < 4; ++k) {
        int idx = t * 4 + k;
        l[k] = s;
        s += (idx < NB) ? bcnt[idx] : 0;
    }
    part[t] = s;
    __syncthreads();
    for (int d = 1; d < 256; d <<= 1) {
        int v = part[t];
        int add = (t >= d) ? part[t - d] : 0;
        __syncthreads();
        part[t] = v + add;
        __syncthreads();
    }
    int excl = t ? part[t - 1] : 0;
#pragma unroll
    for (int k = 0; k < 4; ++k) {
        int idx = t * 4 + k;
        if (idx < NB) { bptr[idx] = excl + l[k]; gcur[idx] = excl + l[k]; }
    }
    if (t == 255) bptr[NB] = part[255];
}

// ---- bin: hist from thist; scatter computes final global dest directly ----
__global__ void k_bin(const int* __restrict__ src, const int* __restrict__ dst, int E,
                      int* __restrict__ gcur, const unsigned short* __restrict__ thist,
                      unsigned* __restrict__ binned) {
    __shared__ unsigned staged[TILE];     // 16 KB
    __shared__ int gscat[TILE];           // 16 KB: final global index per slot
    __shared__ int lstart[NB + 1];
    __shared__ int lcur[NB];
    __shared__ int gbase[NB];
    __shared__ int part[256];
    int t = threadIdx.x;
    int tb = blockIdx.x * TILE;
    int tn = min(TILE, E - tb);
    size_t row = (size_t)blockIdx.x * NB;
    // exclusive scan of this tile's histogram
    int l[4];
    int s = 0;
#pragma unroll
    for (int k = 0; k < 4; ++k) {
        int idx = t * 4 + k;
        l[k] = s;
        s += (idx < NB) ? (int)thist[row + idx] : 0;
    }
    part[t] = s;
    __syncthreads();
    for (int d = 1; d < 256; d <<= 1) {
        int v = part[t];
        int add = (t >= d) ? part[t - d] : 0;
        __syncthreads();
        part[t] = v + add;
        __syncthreads();
    }
    int excl = t ? part[t - 1] : 0;
#pragma unroll
    for (int k = 0; k < 4; ++k) {
        int idx = t * 4 + k;
        if (idx < NB) { int st = excl + l[k]; lstart[idx] = st; lcur[idx] = st; }
    }
    if (t == 255) lstart[NB] = part[255];
    __syncthreads();
    // reserve global runs (one atomic per non-empty bucket per tile)
    for (int i = t; i < NB; i += 256) {
        int c = lstart[i + 1] - lstart[i];
        gbase[i] = (c > 0) ? atomicAdd(&gcur[i], c) : 0;
    }
    __syncthreads();
    // local scatter: record value AND final global destination
    for (int i = t; i < tn; i += 256) {
        int d = dst[tb + i], sv = src[tb + i];
        int b = d >> 7;
        int pos = atomicAdd(&lcur[b], 1);
        staged[pos] = ((unsigned)sv << 7) | (unsigned)(d & 127);
        gscat[pos] = gbase[b] + (pos - lstart[b]);
    }
    __syncthreads();
    // write-out: coalesced LDS reads; global writes coalesced within runs
    for (int j = t; j < tn; j += 256) binned[gscat[j]] = staged[j];
}

// ---- per-bucket: degrees -> dis; padded node-ordered CSR scatter ----
__global__ void k_csr(const int* __restrict__ bptr, const unsigned* __restrict__ binned,
                      float* __restrict__ dis, int* __restrict__ rowptr,
                      int* __restrict__ plen4, int* __restrict__ csr, int n) {
    __shared__ int cnt[128];
    __shared__ int pl[128];
    __shared__ int part[128];
    __shared__ int lbase[128];
    __shared__ int lcur[128];
    int t = threadIdx.x;
    int bk = blockIdx.x;
    int beg = bptr[bk], end = bptr[bk + 1];
    int rbase = (beg & ~3) + 512 * bk;    // 16B-aligned, padding headroom
    if (t < 128) cnt[t] = 0;
    __syncthreads();
    for (int i = beg + t; i < end; i += 256) atomicAdd(&cnt[binned[i] & 127], 1);
    __syncthreads();
    if (t < 128) { pl[t] = (cnt[t] + 3) & ~3; part[t] = pl[t]; }
    __syncthreads();
    for (int d = 1; d < 128; d <<= 1) {
        int v = 0;
        if (t < 128) { v = part[t]; if (t >= d) v += part[t - d]; }
        __syncthreads();
        if (t < 128) part[t] = v;
        __syncthreads();
    }
    if (t < 128) {
        lbase[t] = t ? part[t - 1] : 0;
        lcur[t] = 0;
        int node = (bk << 7) + t;
        if (node < n) {
            int rp = rbase + lbase[t];
            rowptr[node] = rp;
            plen4[node] = pl[t] >> 2;
            dis[node] = rsqrtf((float)cnt[t] + 1.0f);
            for (int k = cnt[t]; k < pl[t]; ++k) csr[rp + k] = n;  // dummy pad
        }
    }
    __syncthreads();
    for (int i = beg + t; i < end; i += 256) {
        unsigned e = binned[i];
        int dloc = e & 127;
        int pos = atomicAdd(&lcur[dloc], 1);
        csr[rbase + lbase[dloc] + pos] = (int)(e >> 7);
    }
}

// ---- featp = (x @ W1) * dis; row n = zeros ----
__global__ void k_xw1(const float* __restrict__ x, const float* __restrict__ W1,
                      const float* __restrict__ dis, float* __restrict__ featp, int n) {
    __shared__ float w[FIN * FHID];   // 8 KB
    for (int i = threadIdx.x; i < FIN * FHID; i += blockDim.x) w[i] = W1[i];
    __syncthreads();
    int r = blockIdx.x * blockDim.x + threadIdx.x;
    if (r > n) return;
    float4* hr = (float4*)(featp + (long long)r * FHID);
    if (r == n) {
        float4 z = make_float4(0.f, 0.f, 0.f, 0.f);
        hr[0] = z; hr[1] = z; hr[2] = z; hr[3] = z;
        return;
    }
    const float4* xr = (const float4*)(x + (long long)r * FIN);
    float acc[FHID];
#pragma unroll
    for (int c = 0; c < FHID; ++c) acc[c] = 0.f;
#pragma unroll 4
    for (int k4 = 0; k4 < FIN / 4; ++k4) {
        float4 xv = xr[k4];
        int k = k4 * 4;
#pragma unroll
        for (int c = 0; c < FHID; ++c) {
            acc[c] += xv.x * w[(k + 0) * FHID + c] + xv.y * w[(k + 1) * FHID + c]
                    + xv.z * w[(k + 2) * FHID + c] + xv.w * w[(k + 3) * FHID + c];
        }
    }
    float d = dis[r];
    hr[0] = make_float4(acc[0] * d, acc[1] * d, acc[2] * d, acc[3] * d);
    hr[1] = make_float4(acc[4] * d, acc[5] * d, acc[6] * d, acc[7] * d);
    hr[2] = make_float4(acc[8] * d, acc[9] * d, acc[10] * d, acc[11] * d);
    hr[3] = make_float4(acc[12] * d, acc[13] * d, acc[14] * d, acc[15] * d);
}

// ---- gather: 4 lanes/node, unroll x2 (8 rows in flight) ----
// L==1: h1p = relu(di*sum + b1)*di      [N,16] (pre-scaled for layer 2)
// L==2: out = (di*sum) @ W2 + b2        [N,32] (W2 fused via shfl collect)
template <int L>
__global__ void k_gather(const int* __restrict__ rowptr, const int* __restrict__ plen4,
                         const int* __restrict__ csr, const float* __restrict__ dis,
                         const float* __restrict__ featp, const float* __restrict__ W2,
                         const float* __restrict__ bias, float* __restrict__ outp, int n) {
    __shared__ float wb[FHID * NACT];
    __shared__ float bs[NACT];
    if (L == 2) {
        for (int i = threadIdx.x; i < FHID * NACT; i += 256) wb[i] = W2[i];
        if (threadIdx.x < NACT) bs[threadIdx.x] = bias[threadIdx.x];
        __syncthreads();
    }
    int t = blockIdx.x * blockDim.x + threadIdx.x;
    int node = t >> 2, p = t & 3;
    if (node > n) return;
    if (node == n) {
        if (L == 1) ((float4*)outp)[(size_t)node * 4 + p] = make_float4(0.f, 0.f, 0.f, 0.f);
        return;
    }
    const float4* fp = (const float4*)featp;
    float4 a = fp[(size_t)node * 4 + p];          // self loop (pre-scaled)
    int beg = rowptr[node];
    int it = plen4[node];
    const int4* cp = (const int4*)(csr + beg);
    int k = 0;
    for (; k + 2 <= it; k += 2) {
        int4 s4 = cp[k];
        int4 s5 = cp[k + 1];
        float4 v0 = fp[(size_t)s4.x * 4 + p];
        float4 v1 = fp[(size_t)s4.y * 4 + p];
        float4 v2 = fp[(size_t)s4.z * 4 + p];
        float4 v3 = fp[(size_t)s4.w * 4 + p];
        float4 v4 = fp[(size_t)s5.x * 4 + p];
        float4 v5 = fp[(size_t)s5.y * 4 + p];
        float4 v6 = fp[(size_t)s5.z * 4 + p];
        float4 v7 = fp[(size_t)s5.w * 4 + p];
        a.x += ((v0.x + v1.x) + (v2.x + v3.x)) + ((v4.x + v5.x) + (v6.x + v7.x));
        a.y += ((v0.y + v1.y) + (v2.y + v3.y)) + ((v4.y + v5.y) + (v6.y + v7.y));
        a.z += ((v0.z + v1.z) + (v2.z + v3.z)) + ((v4.z + v5.z) + (v6.z + v7.z));
        a.w += ((v0.w + v1.w) + (v2.w + v3.w)) + ((v4.w + v5.w) + (v6.w + v7.w));
    }
    if (k < it) {
        int4 s4 = cp[k];
        float4 v0 = fp[(size_t)s4.x * 4 + p];
        float4 v1 = fp[(size_t)s4.y * 4 + p];
        float4 v2 = fp[(size_t)s4.z * 4 + p];
        float4 v3 = fp[(size_t)s4.w * 4 + p];
        a.x += (v0.x + v1.x) + (v2.x + v3.x);
        a.y += (v0.y + v1.y) + (v2.y + v3.y);
        a.z += (v0.z + v1.z) + (v2.z + v3.z);
        a.w += (v0.w + v1.w) + (v2.w + v3.w);
    }
    float di = dis[node];
    if (L == 1) {
        float4 bv = ((const float4*)bias)[p];
        float4 r;
        r.x = fmaxf(di * a.x + bv.x, 0.f) * di;   // pre-scaled for layer 2
        r.y = fmaxf(di * a.y + bv.y, 0.f) * di;
        r.z = fmaxf(di * a.z + bv.z, 0.f) * di;
        r.w = fmaxf(di * a.w + bv.w, 0.f) * di;
        ((float4*)outp)[(size_t)node * 4 + p] = r;
    } else {
        // pre = di*a (this lane holds components 4p..4p+3); collect all 16
        float4 pa = make_float4(di * a.x, di * a.y, di * a.z, di * a.w);
        int base4 = (threadIdx.x & 63) & ~3;
        float p16[16];
#pragma unroll
        for (int q = 0; q < 4; ++q) {
            p16[q * 4 + 0] = __shfl(pa.x, base4 + q, 64);
            p16[q * 4 + 1] = __shfl(pa.y, base4 + q, 64);
            p16[q * 4 + 2] = __shfl(pa.z, base4 + q, 64);
            p16[q * 4 + 3] = __shfl(pa.w, base4 + q, 64);
        }
        float o[8];
#pragma unroll
        for (int j = 0; j < 8; ++j) {
            int col = p * 8 + j;
            float acc = bs[col];
#pragma unroll
            for (int c = 0; c < FHID; ++c) acc += p16[c] * wb[c * NACT + col];
            o[j] = acc;
        }
        ((float4*)outp)[(size_t)node * 8 + p * 2 + 0] = make_float4(o[0], o[1], o[2], o[3]);
        ((float4*)outp)[(size_t)node * 8 + p * 2 + 1] = make_float4(o[4], o[5], o[6], o[7]);
    }
}

extern "C" void kernel_launch(void* const* d_in, const int* in_sizes, int n_in,
                              void* d_out, int out_size, void* d_ws, size_t ws_size,
                              hipStream_t stream) {
    const float* x  = (const float*)d_in[0];
    const float* W1 = (const float*)d_in[1];
    const float* b1 = (const float*)d_in[2];
    const float* W2 = (const float*)d_in[3];
    const float* b2 = (const float*)d_in[4];
    const int*   ei = (const int*)d_in[5];
    const int E = in_sizes[5] / 2;
    const int n = NNODES;
    const int* src = ei;
    const int* dst = ei + E;
    const int ntiles = (E + TILE - 1) / TILE;

    // floats: dis[n] featp[16(n+1)] h1p[16(n+1)]
    // ints:   bcnt[NB] bptr[NB+1] gcur[NB] rowptr[n] plen4[n]
    //         | thist[ntiles*NB] (ushort) | binned[E] | csr[E+512*NB+64]
    float* fb    = (float*)d_ws;
    float* dis   = fb;
    float* featp = fb + (size_t)n;
    float* h1p   = featp + (size_t)16 * (n + 1);
    int*   ib    = (int*)(h1p + (size_t)16 * (n + 1));
    int*   bcnt  = ib;
    int*   bptr  = ib + NB;
    int*   gcur  = ib + 2 * NB + 1;
    int*   rowptr = ib + 3 * NB + 1;
    int*   plen4 = rowptr + n;
    size_t thist_off = (size_t)(3 * NB + 1) + 2 * (size_t)n;          // in ints
    unsigned short* thist = (unsigned short*)(ib + thist_off);
    size_t thist_ints = ((size_t)ntiles * NB + 1) / 2;
    size_t binned_off = thist_off + thist_ints;
    unsigned* binned = (unsigned*)(ib + binned_off);
    size_t csr_off = (binned_off + (size_t)E + 3) & ~(size_t)3;       // 16B-align
    int*   csr   = ib + csr_off;

    (void)hipMemsetAsync(bcnt, 0, NB * sizeof(int), stream);

    const int B = 256;
    k_coarse<<<ntiles, B, 0, stream>>>(dst, E, bcnt, thist);
    k_scan<<<1, B, 0, stream>>>(bcnt, bptr, gcur);
    k_bin<<<ntiles, B, 0, stream>>>(src, dst, E, gcur, thist, binned);
    k_csr<<<NB, B, 0, stream>>>(bptr, binned, dis, rowptr, plen4, csr, n);
    k_xw1<<<(n + 1 + B - 1) / B, B, 0, stream>>>(x, W1, dis, featp, n);
    k_gather<1><<<((n + 1) * 4 + B - 1) / B, B, 0, stream>>>(rowptr, plen4, csr, dis, featp,
                                                             nullptr, b1, h1p, n);
    k_gather<2><<<((n + 1) * 4 + B - 1) / B, B, 0, stream>>>(rowptr, plen4, csr, dis, h1p,
                                                             W2, b2, (float*)d_out, n);
}

// Round 7
// 288.678 us; speedup vs baseline: 3.0234x; 1.0440x over previous
//
#include <hip/hip_runtime.h>

// QNetGNN: 2-layer GCN, N=100000, E=3.2M, F: 128 -> 16 -> 32.
// R7: k_bin/k_csr at 512 threads (same LDS -> 2x waves/CU: latency-bound
// kernels need waves, not smaller tiles); gather unroll x4 (16 float4 loads
// in flight); k_xw1 float4 LDS weight reads. Pre-scaled features
// (featp = h*dis); self loop = own row; dummy row n = zeros for padding.

#define NNODES 100000
#define FIN    128
#define FHID   16
#define NACT   32
#define NB     782          // ceil(100000/128) buckets of 128 dst nodes
#define TILE   4096

// ---- coarse histogram of dst buckets; also store per-tile hist (ushort) ----
__global__ void k_coarse(const int* __restrict__ dst, int E, int* __restrict__ bcnt,
                         unsigned short* __restrict__ thist) {
    __shared__ int hist[NB];
    int t = threadIdx.x;
    int tb = blockIdx.x * TILE;
    int tn = min(TILE, E - tb);
    for (int i = t; i < NB; i += 256) hist[i] = 0;
    __syncthreads();
    for (int i = t; i < tn; i += 256) atomicAdd(&hist[dst[tb + i] >> 7], 1);
    __syncthreads();
    size_t row = (size_t)blockIdx.x * NB;
    for (int i = t; i < NB; i += 256) {
        int hv = hist[i];
        thist[row + i] = (unsigned short)hv;
        if (hv) atomicAdd(&bcnt[i], hv);
    }
}

__global__ void k_scan(const int* __restrict__ bcnt, int* __restrict__ bptr,
                       int* __restrict__ gcur) {
    __shared__ int part[256];
    int t = threadIdx.x;
    int l[4];
    int s = 0;
#pragma unroll
    for (int k = 0; k < 4; ++k) {
        int idx = t * 4 + k;
        l[k] = s;
        s += (idx < NB) ? bcnt[idx] : 0;
    }
    part[t] = s;
    __syncthreads();
    for (int d = 1; d < 256; d <<= 1) {
        int v = part[t];
        int add = (t >= d) ? part[t - d] : 0;
        __syncthreads();
        part[t] = v + add;
        __syncthreads();
    }
    int excl = t ? part[t - 1] : 0;
#pragma unroll
    for (int k = 0; k < 4; ++k) {
        int idx = t * 4 + k;
        if (idx < NB) { bptr[idx] = excl + l[k]; gcur[idx] = excl + l[k]; }
    }
    if (t == 255) bptr[NB] = part[255];
}

// ---- bin: 512 threads; scatter computes final global dest directly ----
__global__ void __launch_bounds__(512) k_bin(
        const int* __restrict__ src, const int* __restrict__ dst, int E,
        int* __restrict__ gcur, const unsigned short* __restrict__ thist,
        unsigned* __restrict__ binned) {
    __shared__ unsigned staged[TILE];     // 16 KB
    __shared__ int gscat[TILE];           // 16 KB
    __shared__ int lstart[NB + 1];
    __shared__ int lcur[NB];
    __shared__ int gbase[NB];
    __shared__ int part[512];
    int t = threadIdx.x;
    int tb = blockIdx.x * TILE;
    int tn = min(TILE, E - tb);
    size_t row = (size_t)blockIdx.x * NB;
    // exclusive scan of this tile's histogram: 2 entries per thread
    int i0 = t * 2, i1 = t * 2 + 1;
    int c0 = (i0 < NB) ? (int)thist[row + i0] : 0;
    int c1 = (i1 < NB) ? (int)thist[row + i1] : 0;
    part[t] = c0 + c1;
    __syncthreads();
    for (int d = 1; d < 512; d <<= 1) {
        int v = part[t];
        int add = (t >= d) ? part[t - d] : 0;
        __syncthreads();
        part[t] = v + add;
        __syncthreads();
    }
    int excl = t ? part[t - 1] : 0;
    if (i0 < NB) { lstart[i0] = excl;      lcur[i0] = excl; }
    if (i1 < NB) { lstart[i1] = excl + c0; lcur[i1] = excl + c0; }
    if (t == 511) lstart[NB] = part[511];
    __syncthreads();
    // reserve global runs (one atomic per non-empty bucket per tile)
    for (int i = t; i < NB; i += 512) {
        int c = lstart[i + 1] - lstart[i];
        gbase[i] = (c > 0) ? atomicAdd(&gcur[i], c) : 0;
    }
    __syncthreads();
    // local scatter: record value AND final global destination
    for (int i = t; i < tn; i += 512) {
        int d = dst[tb + i], sv = src[tb + i];
        int b = d >> 7;
        int pos = atomicAdd(&lcur[b], 1);
        staged[pos] = ((unsigned)sv << 7) | (unsigned)(d & 127);
        gscat[pos] = gbase[b] + (pos - lstart[b]);
    }
    __syncthreads();
    // write-out: coalesced LDS reads; global writes coalesced within runs
    for (int j = t; j < tn; j += 512) binned[gscat[j]] = staged[j];
}

// ---- per-bucket: degrees -> dis; padded node-ordered CSR scatter ----
__global__ void __launch_bounds__(512) k_csr(
        const int* __restrict__ bptr, const unsigned* __restrict__ binned,
        float* __restrict__ dis, int* __restrict__ rowptr,
        int* __restrict__ plen4, int* __restrict__ csr, int n) {
    __shared__ int cnt[128];
    __shared__ int pl[128];
    __shared__ int part[128];
    __shared__ int lbase[128];
    __shared__ int lcur[128];
    int t = threadIdx.x;
    int bk = blockIdx.x;
    int beg = bptr[bk], end = bptr[bk + 1];
    int rbase = (beg & ~3) + 512 * bk;    // 16B-aligned, padding headroom
    if (t < 128) cnt[t] = 0;
    __syncthreads();
    for (int i = beg + t; i < end; i += 512) atomicAdd(&cnt[binned[i] & 127], 1);
    __syncthreads();
    if (t < 128) { pl[t] = (cnt[t] + 3) & ~3; part[t] = pl[t]; }
    __syncthreads();
    for (int d = 1; d < 128; d <<= 1) {
        int v = 0;
        if (t < 128) { v = part[t]; if (t >= d) v += part[t - d]; }
        __syncthreads();
        if (t < 128) part[t] = v;
        __syncthreads();
    }
    if (t < 128) {
        lbase[t] = t ? part[t - 1] : 0;
        lcur[t] = 0;
        int node = (bk << 7) + t;
        if (node < n) {
            int rp = rbase + lbase[t];
            rowptr[node] = rp;
            plen4[node] = pl[t] >> 2;
            dis[node] = rsqrtf((float)cnt[t] + 1.0f);
            for (int k = cnt[t]; k < pl[t]; ++k) csr[rp + k] = n;  // dummy pad
        }
    }
    __syncthreads();
    for (int i = beg + t; i < end; i += 512) {
        unsigned e = binned[i];
        int dloc = e & 127;
        int pos = atomicAdd(&lcur[dloc], 1);
        csr[rbase + lbase[dloc] + pos] = (int)(e >> 7);
    }
}

#define FMA4(A, S, W) { (A).x += (S) * (W).x; (A).y += (S) * (W).y; \
                        (A).z += (S) * (W).z; (A).w += (S) * (W).w; }

// ---- featp = (x @ W1) * dis; row n = zeros ----
__global__ void k_xw1(const float* __restrict__ x, const float* __restrict__ W1,
                      const float* __restrict__ dis, float* __restrict__ featp, int n) {
    __shared__ float w[FIN * FHID];   // 8 KB, row-major [128][16]
    for (int i = threadIdx.x; i < FIN * FHID; i += blockDim.x) w[i] = W1[i];
    __syncthreads();
    int r = blockIdx.x * blockDim.x + threadIdx.x;
    if (r > n) return;
    float4* hr = (float4*)(featp + (long long)r * FHID);
    if (r == n) {
        float4 z = make_float4(0.f, 0.f, 0.f, 0.f);
        hr[0] = z; hr[1] = z; hr[2] = z; hr[3] = z;
        return;
    }
    const float4* xr = (const float4*)(x + (long long)r * FIN);
    const float4* w4 = (const float4*)w;      // [128][4] float4s
    float4 a0 = make_float4(0.f, 0.f, 0.f, 0.f), a1 = a0, a2 = a0, a3 = a0;
#pragma unroll 8
    for (int k4 = 0; k4 < FIN / 4; ++k4) {
        float4 xv = xr[k4];
        int kb = k4 * 16;                     // float4 index of row k4*4
        FMA4(a0, xv.x, w4[kb + 0]);  FMA4(a1, xv.x, w4[kb + 1]);
        FMA4(a2, xv.x, w4[kb + 2]);  FMA4(a3, xv.x, w4[kb + 3]);
        FMA4(a0, xv.y, w4[kb + 4]);  FMA4(a1, xv.y, w4[kb + 5]);
        FMA4(a2, xv.y, w4[kb + 6]);  FMA4(a3, xv.y, w4[kb + 7]);
        FMA4(a0, xv.z, w4[kb + 8]);  FMA4(a1, xv.z, w4[kb + 9]);
        FMA4(a2, xv.z, w4[kb + 10]); FMA4(a3, xv.z, w4[kb + 11]);
        FMA4(a0, xv.w, w4[kb + 12]); FMA4(a1, xv.w, w4[kb + 13]);
        FMA4(a2, xv.w, w4[kb + 14]); FMA4(a3, xv.w, w4[kb + 15]);
    }
    float d = dis[r];
    hr[0] = make_float4(a0.x * d, a0.y * d, a0.z * d, a0.w * d);
    hr[1] = make_float4(a1.x * d, a1.y * d, a1.z * d, a1.w * d);
    hr[2] = make_float4(a2.x * d, a2.y * d, a2.z * d, a2.w * d);
    hr[3] = make_float4(a3.x * d, a3.y * d, a3.z * d, a3.w * d);
}

// ---- gather: 4 lanes/node, unroll x4 (16 float4 rows in flight) ----
// L==1: h1p = relu(di*sum + b1)*di      [N,16] (pre-scaled for layer 2)
// L==2: out = (di*sum) @ W2 + b2        [N,32] (W2 fused via shfl collect)
template <int L>
__global__ void k_gather(const int* __restrict__ rowptr, const int* __restrict__ plen4,
                         const int* __restrict__ csr, const float* __restrict__ dis,
                         const float* __restrict__ featp, const float* __restrict__ W2,
                         const float* __restrict__ bias, float* __restrict__ outp, int n) {
    __shared__ float wb[FHID * NACT];
    __shared__ float bs[NACT];
    if (L == 2) {
        for (int i = threadIdx.x; i < FHID * NACT; i += 256) wb[i] = W2[i];
        if (threadIdx.x < NACT) bs[threadIdx.x] = bias[threadIdx.x];
        __syncthreads();
    }
    int t = blockIdx.x * blockDim.x + threadIdx.x;
    int node = t >> 2, p = t & 3;
    if (node > n) return;
    if (node == n) {
        if (L == 1) ((float4*)outp)[(size_t)node * 4 + p] = make_float4(0.f, 0.f, 0.f, 0.f);
        return;
    }
    const float4* fp = (const float4*)featp;
    float4 a = fp[(size_t)node * 4 + p];          // self loop (pre-scaled)
    float4 b = make_float4(0.f, 0.f, 0.f, 0.f);
    int beg = rowptr[node];
    int it = plen4[node];
    const int4* cp = (const int4*)(csr + beg);
    int k = 0;
    for (; k + 4 <= it; k += 4) {
        int4 s0 = cp[k], s1 = cp[k + 1], s2 = cp[k + 2], s3 = cp[k + 3];
        float4 v0 = fp[(size_t)s0.x * 4 + p];
        float4 v1 = fp[(size_t)s0.y * 4 + p];
        float4 v2 = fp[(size_t)s0.z * 4 + p];
        float4 v3 = fp[(size_t)s0.w * 4 + p];
        float4 v4 = fp[(size_t)s1.x * 4 + p];
        float4 v5 = fp[(size_t)s1.y * 4 + p];
        float4 v6 = fp[(size_t)s1.z * 4 + p];
        float4 v7 = fp[(size_t)s1.w * 4 + p];
        float4 v8 = fp[(size_t)s2.x * 4 + p];
        float4 v9 = fp[(size_t)s2.y * 4 + p];
        float4 va = fp[(size_t)s2.z * 4 + p];
        float4 vb = fp[(size_t)s2.w * 4 + p];
        float4 vc = fp[(size_t)s3.x * 4 + p];
        float4 vd = fp[(size_t)s3.y * 4 + p];
        float4 ve = fp[(size_t)s3.z * 4 + p];
        float4 vf = fp[(size_t)s3.w * 4 + p];
        a.x += ((v0.x + v1.x) + (v2.x + v3.x)) + ((v4.x + v5.x) + (v6.x + v7.x));
        a.y += ((v0.y + v1.y) + (v2.y + v3.y)) + ((v4.y + v5.y) + (v6.y + v7.y));
        a.z += ((v0.z + v1.z) + (v2.z + v3.z)) + ((v4.z + v5.z) + (v6.z + v7.z));
        a.w += ((v0.w + v1.w) + (v2.w + v3.w)) + ((v4.w + v5.w) + (v6.w + v7.w));
        b.x += ((v8.x + v9.x) + (va.x + vb.x)) + ((vc.x + vd.x) + (ve.x + vf.x));
        b.y += ((v8.y + v9.y) + (va.y + vb.y)) + ((vc.y + vd.y) + (ve.y + vf.y));
        b.z += ((v8.z + v9.z) + (va.z + vb.z)) + ((vc.z + vd.z) + (ve.z + vf.z));
        b.w += ((v8.w + v9.w) + (va.w + vb.w)) + ((vc.w + vd.w) + (ve.w + vf.w));
    }
    for (; k < it; ++k) {
        int4 s4 = cp[k];
        float4 v0 = fp[(size_t)s4.x * 4 + p];
        float4 v1 = fp[(size_t)s4.y * 4 + p];
        float4 v2 = fp[(size_t)s4.z * 4 + p];
        float4 v3 = fp[(size_t)s4.w * 4 + p];
        a.x += (v0.x + v1.x) + (v2.x + v3.x);
        a.y += (v0.y + v1.y) + (v2.y + v3.y);
        a.z += (v0.z + v1.z) + (v2.z + v3.z);
        a.w += (v0.w + v1.w) + (v2.w + v3.w);
    }
    a.x += b.x; a.y += b.y; a.z += b.z; a.w += b.w;
    float di = dis[node];
    if (L == 1) {
        float4 bv = ((const float4*)bias)[p];
        float4 r;
        r.x = fmaxf(di * a.x + bv.x, 0.f) * di;   // pre-scaled for layer 2
        r.y = fmaxf(di * a.y + bv.y, 0.f) * di;
        r.z = fmaxf(di * a.z + bv.z, 0.f) * di;
        r.w = fmaxf(di * a.w + bv.w, 0.f) * di;
        ((float4*)outp)[(size_t)node * 4 + p] = r;
    } else {
        float4 pa = make_float4(di * a.x, di * a.y, di * a.z, di * a.w);
        int base4 = (threadIdx.x & 63) & ~3;
        float p16[16];
#pragma unroll
        for (int q = 0; q < 4; ++q) {
            p16[q * 4 + 0] = __shfl(pa.x, base4 + q, 64);
            p16[q * 4 + 1] = __shfl(pa.y, base4 + q, 64);
            p16[q * 4 + 2] = __shfl(pa.z, base4 + q, 64);
            p16[q * 4 + 3] = __shfl(pa.w, base4 + q, 64);
        }
        float o[8];
#pragma unroll
        for (int j = 0; j < 8; ++j) {
            int col = p * 8 + j;
            float acc = bs[col];
#pragma unroll
            for (int c = 0; c < FHID; ++c) acc += p16[c] * wb[c * NACT + col];
            o[j] = acc;
        }
        ((float4*)outp)[(size_t)node * 8 + p * 2 + 0] = make_float4(o[0], o[1], o[2], o[3]);
        ((float4*)outp)[(size_t)node * 8 + p * 2 + 1] = make_float4(o[4], o[5], o[6], o[7]);
    }
}

extern "C" void kernel_launch(void* const* d_in, const int* in_sizes, int n_in,
                              void* d_out, int out_size, void* d_ws, size_t ws_size,
                              hipStream_t stream) {
    const float* x  = (const float*)d_in[0];
    const float* W1 = (const float*)d_in[1];
    const float* b1 = (const float*)d_in[2];
    const float* W2 = (const float*)d_in[3];
    const float* b2 = (const float*)d_in[4];
    const int*   ei = (const int*)d_in[5];
    const int E = in_sizes[5] / 2;
    const int n = NNODES;
    const int* src = ei;
    const int* dst = ei + E;
    const int ntiles = (E + TILE - 1) / TILE;

    // floats: dis[n] featp[16(n+1)] h1p[16(n+1)]
    // ints:   bcnt[NB] bptr[NB+1] gcur[NB] rowptr[n] plen4[n]
    //         | thist[ntiles*NB] (ushort) | binned[E] | csr[E+512*NB+64]
    float* fb    = (float*)d_ws;
    float* dis   = fb;
    float* featp = fb + (size_t)n;
    float* h1p   = featp + (size_t)16 * (n + 1);
    int*   ib    = (int*)(h1p + (size_t)16 * (n + 1));
    int*   bcnt  = ib;
    int*   bptr  = ib + NB;
    int*   gcur  = ib + 2 * NB + 1;
    int*   rowptr = ib + 3 * NB + 1;
    int*   plen4 = rowptr + n;
    size_t thist_off = (size_t)(3 * NB + 1) + 2 * (size_t)n;          // in ints
    unsigned short* thist = (unsigned short*)(ib + thist_off);
    size_t thist_ints = ((size_t)ntiles * NB + 1) / 2;
    size_t binned_off = thist_off + thist_ints;
    unsigned* binned = (unsigned*)(ib + binned_off);
    size_t csr_off = (binned_off + (size_t)E + 3) & ~(size_t)3;       // 16B-align
    int*   csr   = ib + csr_off;

    (void)hipMemsetAsync(bcnt, 0, NB * sizeof(int), stream);

    const int B = 256;
    k_coarse<<<ntiles, B, 0, stream>>>(dst, E, bcnt, thist);
    k_scan<<<1, B, 0, stream>>>(bcnt, bptr, gcur);
    k_bin<<<ntiles, 512, 0, stream>>>(src, dst, E, gcur, thist, binned);
    k_csr<<<NB, 512, 0, stream>>>(bptr, binned, dis, rowptr, plen4, csr, n);
    k_xw1<<<(n + 1 + B - 1) / B, B, 0, stream>>>(x, W1, dis, featp, n);
    k_gather<1><<<((n + 1) * 4 + B - 1) / B, B, 0, stream>>>(rowptr, plen4, csr, dis, featp,
                                                             nullptr, b1, h1p, n);
    k_gather<2><<<((n + 1) * 4 + B - 1) / B, B, 0, stream>>>(rowptr, plen4, csr, dis, h1p,
                                                             W2, b2, (float*)d_out, n);
}

// Round 8
// 277.989 us; speedup vs baseline: 3.1397x; 1.0385x over previous
//
#include <hip/hip_runtime.h>
#include <hip/hip_fp16.h>

// QNetGNN: 2-layer GCN, N=100000, E=3.2M, F: 128 -> 16 -> 32.
// R8: (a) k_bin v3 = direct global scatter (no staged/gscat LDS round-trips,
// ~11 KB LDS -> full occupancy); (b) fp16 feature tables (3.2 MB -> fits one
// XCD L2; fp32 accumulation); (c) csr entries pre-shifted (node*4) to save
// addr VALU in gather. Pre-scaled features (featp = h*dis); self loop = own
// row; dummy row n = zeros for padding.

#define NNODES 100000
#define FIN    128
#define FHID   16
#define NACT   32
#define NB     782          // ceil(100000/128) buckets of 128 dst nodes
#define TILE   4096

// ---- coarse histogram of dst buckets; also store per-tile hist (ushort) ----
__global__ void k_coarse(const int* __restrict__ dst, int E, int* __restrict__ bcnt,
                         unsigned short* __restrict__ thist) {
    __shared__ int hist[NB];
    int t = threadIdx.x;
    int tb = blockIdx.x * TILE;
    int tn = min(TILE, E - tb);
    for (int i = t; i < NB; i += 256) hist[i] = 0;
    __syncthreads();
    for (int i = t; i < tn; i += 256) atomicAdd(&hist[dst[tb + i] >> 7], 1);
    __syncthreads();
    size_t row = (size_t)blockIdx.x * NB;
    for (int i = t; i < NB; i += 256) {
        int hv = hist[i];
        thist[row + i] = (unsigned short)hv;
        if (hv) atomicAdd(&bcnt[i], hv);
    }
}

__global__ void k_scan(const int* __restrict__ bcnt, int* __restrict__ bptr,
                       int* __restrict__ gcur) {
    __shared__ int part[256];
    int t = threadIdx.x;
    int l[4];
    int s = 0;
#pragma unroll
    for (int k = 0; k < 4; ++k) {
        int idx = t * 4 + k;
        l[k] = s;
        s += (idx < NB) ? bcnt[idx] : 0;
    }
    part[t] = s;
    __syncthreads();
    for (int d = 1; d < 256; d <<= 1) {
        int v = part[t];
        int add = (t >= d) ? part[t - d] : 0;
        __syncthreads();
        part[t] = v + add;
        __syncthreads();
    }
    int excl = t ? part[t - 1] : 0;
#pragma unroll
    for (int k = 0; k < 4; ++k) {
        int idx = t * 4 + k;
        if (idx < NB) { bptr[idx] = excl + l[k]; gcur[idx] = excl + l[k]; }
    }
    if (t == 255) bptr[NB] = part[255];
}

// ---- bin v3: direct global scatter; tiny LDS -> max waves ----
__global__ void __launch_bounds__(512) k_bin(
        const int* __restrict__ src, const int* __restrict__ dst, int E,
        int* __restrict__ gcur, const unsigned short* __restrict__ thist,
        unsigned* __restrict__ binned) {
    __shared__ int lstart[NB + 1];
    __shared__ int lcur[NB];
    __shared__ int gbase[NB];
    __shared__ int part[512];
    int t = threadIdx.x;
    int tb = blockIdx.x * TILE;
    int tn = min(TILE, E - tb);
    size_t row = (size_t)blockIdx.x * NB;
    // exclusive scan of this tile's histogram: 2 entries per thread
    int i0 = t * 2, i1 = t * 2 + 1;
    int c0 = (i0 < NB) ? (int)thist[row + i0] : 0;
    int c1 = (i1 < NB) ? (int)thist[row + i1] : 0;
    part[t] = c0 + c1;
    __syncthreads();
    for (int d = 1; d < 512; d <<= 1) {
        int v = part[t];
        int add = (t >= d) ? part[t - d] : 0;
        __syncthreads();
        part[t] = v + add;
        __syncthreads();
    }
    int excl = t ? part[t - 1] : 0;
    if (i0 < NB) { lstart[i0] = excl;      lcur[i0] = excl; }
    if (i1 < NB) { lstart[i1] = excl + c0; lcur[i1] = excl + c0; }
    if (t == 511) lstart[NB] = part[511];
    __syncthreads();
    // reserve global runs (one atomic per non-empty bucket per tile)
    for (int i = t; i < NB; i += 512) {
        int c = lstart[i + 1] - lstart[i];
        gbase[i] = (c > 0) ? atomicAdd(&gcur[i], c) : 0;
    }
    __syncthreads();
    // scatter straight to global run positions
    for (int i = t; i < tn; i += 512) {
        int d = dst[tb + i], sv = src[tb + i];
        int b = d >> 7;
        int pos = atomicAdd(&lcur[b], 1);
        binned[gbase[b] + (pos - lstart[b])] = ((unsigned)sv << 7) | (unsigned)(d & 127);
    }
}

// ---- per-bucket: degrees -> dis; padded node-ordered CSR (entries = src*4) ----
__global__ void __launch_bounds__(512) k_csr(
        const int* __restrict__ bptr, const unsigned* __restrict__ binned,
        float* __restrict__ dis, int* __restrict__ rowptr,
        int* __restrict__ plen4, int* __restrict__ csr, int n) {
    __shared__ int cnt[128];
    __shared__ int pl[128];
    __shared__ int part[128];
    __shared__ int lbase[128];
    __shared__ int lcur[128];
    int t = threadIdx.x;
    int bk = blockIdx.x;
    int beg = bptr[bk], end = bptr[bk + 1];
    int rbase = (beg & ~3) + 512 * bk;    // 16B-aligned, padding headroom
    if (t < 128) cnt[t] = 0;
    __syncthreads();
    for (int i = beg + t; i < end; i += 512) atomicAdd(&cnt[binned[i] & 127], 1);
    __syncthreads();
    if (t < 128) { pl[t] = (cnt[t] + 3) & ~3; part[t] = pl[t]; }
    __syncthreads();
    for (int d = 1; d < 128; d <<= 1) {
        int v = 0;
        if (t < 128) { v = part[t]; if (t >= d) v += part[t - d]; }
        __syncthreads();
        if (t < 128) part[t] = v;
        __syncthreads();
    }
    if (t < 128) {
        lbase[t] = t ? part[t - 1] : 0;
        lcur[t] = 0;
        int node = (bk << 7) + t;
        if (node < n) {
            int rp = rbase + lbase[t];
            rowptr[node] = rp;
            plen4[node] = pl[t] >> 2;
            dis[node] = rsqrtf((float)cnt[t] + 1.0f);
            for (int k = cnt[t]; k < pl[t]; ++k) csr[rp + k] = n << 2;  // dummy pad
        }
    }
    __syncthreads();
    for (int i = beg + t; i < end; i += 512) {
        unsigned e = binned[i];
        int dloc = e & 127;
        int pos = atomicAdd(&lcur[dloc], 1);
        csr[rbase + lbase[dloc] + pos] = (int)(e >> 7) << 2;   // pre-shifted
    }
}

#define FMA4(A, S, W) { (A).x += (S) * (W).x; (A).y += (S) * (W).y; \
                        (A).z += (S) * (W).z; (A).w += (S) * (W).w; }

__device__ __forceinline__ unsigned pack2(float a, float b) {
    __half2 h = __floats2half2_rn(a, b);
    return *reinterpret_cast<unsigned*>(&h);
}

// ---- featp = fp16((x @ W1) * dis); row n = zeros ----
__global__ void k_xw1(const float* __restrict__ x, const float* __restrict__ W1,
                      const float* __restrict__ dis, __half* __restrict__ featp, int n) {
    __shared__ float w[FIN * FHID];   // 8 KB, row-major [128][16]
    for (int i = threadIdx.x; i < FIN * FHID; i += blockDim.x) w[i] = W1[i];
    __syncthreads();
    int r = blockIdx.x * blockDim.x + threadIdx.x;
    if (r > n) return;
    uint4* hr = (uint4*)(featp + (size_t)r * FHID);   // 32 B row = 2 uint4
    if (r == n) {
        uint4 z = make_uint4(0u, 0u, 0u, 0u);
        hr[0] = z; hr[1] = z;
        return;
    }
    const float4* xr = (const float4*)(x + (long long)r * FIN);
    const float4* w4 = (const float4*)w;      // [128][4] float4s
    float4 a0 = make_float4(0.f, 0.f, 0.f, 0.f), a1 = a0, a2 = a0, a3 = a0;
#pragma unroll 8
    for (int k4 = 0; k4 < FIN / 4; ++k4) {
        float4 xv = xr[k4];
        int kb = k4 * 16;
        FMA4(a0, xv.x, w4[kb + 0]);  FMA4(a1, xv.x, w4[kb + 1]);
        FMA4(a2, xv.x, w4[kb + 2]);  FMA4(a3, xv.x, w4[kb + 3]);
        FMA4(a0, xv.y, w4[kb + 4]);  FMA4(a1, xv.y, w4[kb + 5]);
        FMA4(a2, xv.y, w4[kb + 6]);  FMA4(a3, xv.y, w4[kb + 7]);
        FMA4(a0, xv.z, w4[kb + 8]);  FMA4(a1, xv.z, w4[kb + 9]);
        FMA4(a2, xv.z, w4[kb + 10]); FMA4(a3, xv.z, w4[kb + 11]);
        FMA4(a0, xv.w, w4[kb + 12]); FMA4(a1, xv.w, w4[kb + 13]);
        FMA4(a2, xv.w, w4[kb + 14]); FMA4(a3, xv.w, w4[kb + 15]);
    }
    float d = dis[r];
    uint4 w0, w1;
    w0.x = pack2(a0.x * d, a0.y * d); w0.y = pack2(a0.z * d, a0.w * d);
    w0.z = pack2(a1.x * d, a1.y * d); w0.w = pack2(a1.z * d, a1.w * d);
    w1.x = pack2(a2.x * d, a2.y * d); w1.y = pack2(a2.z * d, a2.w * d);
    w1.z = pack2(a3.x * d, a3.y * d); w1.w = pack2(a3.z * d, a3.w * d);
    hr[0] = w0; hr[1] = w1;
}

#define ACC8(U) { \
    __half2 h0_ = *reinterpret_cast<__half2*>(&(U).x); \
    __half2 h1_ = *reinterpret_cast<__half2*>(&(U).y); \
    float2 f0_ = __half22float2(h0_); \
    float2 f1_ = __half22float2(h1_); \
    a.x += f0_.x; a.y += f0_.y; a.z += f1_.x; a.w += f1_.y; }

// ---- gather: 4 lanes/node, fp16 rows (8 B/lane), unroll x4 ----
// csr entries are src*4; lane reads uint2 at fp[entry + p].
// L==1: h1p = fp16(relu(di*sum + b1)*di)   [N,16]
// L==2: out = (di*sum) @ W2 + b2           [N,32] fp32 (W2 fused via shfl)
template <int L>
__global__ void __launch_bounds__(256, 6) k_gather(
        const int* __restrict__ rowptr, const int* __restrict__ plen4,
        const int* __restrict__ csr, const float* __restrict__ dis,
        const __half* __restrict__ featp, const float* __restrict__ W2,
        const float* __restrict__ bias, void* __restrict__ outp, int n) {
    __shared__ float wb[FHID * NACT];
    __shared__ float bs[NACT];
    if (L == 2) {
        for (int i = threadIdx.x; i < FHID * NACT; i += 256) wb[i] = W2[i];
        if (threadIdx.x < NACT) bs[threadIdx.x] = bias[threadIdx.x];
        __syncthreads();
    }
    int t = blockIdx.x * blockDim.x + threadIdx.x;
    int node = t >> 2, p = t & 3;
    if (node > n) return;
    const uint2* fp = (const uint2*)featp;    // 4 granules of 8 B per row
    if (node == n) {
        if (L == 1) ((uint2*)outp)[(size_t)node * 4 + p] = make_uint2(0u, 0u);
        return;
    }
    float4 a = make_float4(0.f, 0.f, 0.f, 0.f);
    {   // self loop (pre-scaled)
        uint2 u = fp[(size_t)(node << 2) + p];
        ACC8(u);
    }
    int beg = rowptr[node];
    int it = plen4[node];
    const int4* cp = (const int4*)(csr + beg);
    int k = 0;
    for (; k + 4 <= it; k += 4) {
        int4 s0 = cp[k], s1 = cp[k + 1], s2 = cp[k + 2], s3 = cp[k + 3];
        uint2 u0 = fp[(size_t)s0.x + p];
        uint2 u1 = fp[(size_t)s0.y + p];
        uint2 u2 = fp[(size_t)s0.z + p];
        uint2 u3 = fp[(size_t)s0.w + p];
        uint2 u4 = fp[(size_t)s1.x + p];
        uint2 u5 = fp[(size_t)s1.y + p];
        uint2 u6 = fp[(size_t)s1.z + p];
        uint2 u7 = fp[(size_t)s1.w + p];
        uint2 u8 = fp[(size_t)s2.x + p];
        uint2 u9 = fp[(size_t)s2.y + p];
        uint2 ua = fp[(size_t)s2.z + p];
        uint2 ub = fp[(size_t)s2.w + p];
        uint2 uc = fp[(size_t)s3.x + p];
        uint2 ud = fp[(size_t)s3.y + p];
        uint2 ue = fp[(size_t)s3.z + p];
        uint2 uf = fp[(size_t)s3.w + p];
        ACC8(u0); ACC8(u1); ACC8(u2); ACC8(u3);
        ACC8(u4); ACC8(u5); ACC8(u6); ACC8(u7);
        ACC8(u8); ACC8(u9); ACC8(ua); ACC8(ub);
        ACC8(uc); ACC8(ud); ACC8(ue); ACC8(uf);
    }
    for (; k < it; ++k) {
        int4 s4 = cp[k];
        uint2 u0 = fp[(size_t)s4.x + p];
        uint2 u1 = fp[(size_t)s4.y + p];
        uint2 u2 = fp[(size_t)s4.z + p];
        uint2 u3 = fp[(size_t)s4.w + p];
        ACC8(u0); ACC8(u1); ACC8(u2); ACC8(u3);
    }
    float di = dis[node];
    if (L == 1) {
        float4 bv = ((const float4*)bias)[p];
        float rx = fmaxf(di * a.x + bv.x, 0.f) * di;   // pre-scaled for layer 2
        float ry = fmaxf(di * a.y + bv.y, 0.f) * di;
        float rz = fmaxf(di * a.z + bv.z, 0.f) * di;
        float rw = fmaxf(di * a.w + bv.w, 0.f) * di;
        uint2 w;
        w.x = pack2(rx, ry);
        w.y = pack2(rz, rw);
        ((uint2*)outp)[(size_t)node * 4 + p] = w;
    } else {
        float4 pa = make_float4(di * a.x, di * a.y, di * a.z, di * a.w);
        int base4 = (threadIdx.x & 63) & ~3;
        float p16[16];
#pragma unroll
        for (int q = 0; q < 4; ++q) {
            p16[q * 4 + 0] = __shfl(pa.x, base4 + q, 64);
            p16[q * 4 + 1] = __shfl(pa.y, base4 + q, 64);
            p16[q * 4 + 2] = __shfl(pa.z, base4 + q, 64);
            p16[q * 4 + 3] = __shfl(pa.w, base4 + q, 64);
        }
        float o[8];
#pragma unroll
        for (int j = 0; j < 8; ++j) {
            int col = p * 8 + j;
            float acc = bs[col];
#pragma unroll
            for (int c = 0; c < FHID; ++c) acc += p16[c] * wb[c * NACT + col];
            o[j] = acc;
        }
        ((float4*)outp)[(size_t)node * 8 + p * 2 + 0] = make_float4(o[0], o[1], o[2], o[3]);
        ((float4*)outp)[(size_t)node * 8 + p * 2 + 1] = make_float4(o[4], o[5], o[6], o[7]);
    }
}

extern "C" void kernel_launch(void* const* d_in, const int* in_sizes, int n_in,
                              void* d_out, int out_size, void* d_ws, size_t ws_size,
                              hipStream_t stream) {
    const float* x  = (const float*)d_in[0];
    const float* W1 = (const float*)d_in[1];
    const float* b1 = (const float*)d_in[2];
    const float* W2 = (const float*)d_in[3];
    const float* b2 = (const float*)d_in[4];
    const int*   ei = (const int*)d_in[5];
    const int E = in_sizes[5] / 2;
    const int n = NNODES;
    const int npad = n + 8;               // keeps fp16 tables 16B-aligned
    const int* src = ei;
    const int* dst = ei + E;
    const int ntiles = (E + TILE - 1) / TILE;

    // floats: dis[n] | featp fp16 [16*npad] | h1p fp16 [16*npad]
    // ints:   bcnt[NB] bptr[NB+1] gcur[NB] rowptr[n] plen4[n]
    //         | thist[ntiles*NB] ushort | binned[E] | csr[E+512*NB+64]
    float* fb    = (float*)d_ws;
    float* dis   = fb;
    __half* featp = (__half*)(fb + (size_t)n);
    __half* h1p   = featp + (size_t)16 * npad;
    int*   ib    = (int*)(h1p + (size_t)16 * npad);
    int*   bcnt  = ib;
    int*   bptr  = ib + NB;
    int*   gcur  = ib + 2 * NB + 1;
    int*   rowptr = ib + 3 * NB + 1;
    int*   plen4 = rowptr + n;
    size_t thist_off = (size_t)(3 * NB + 1) + 2 * (size_t)n;          // in ints
    unsigned short* thist = (unsigned short*)(ib + thist_off);
    size_t thist_ints = ((size_t)ntiles * NB + 1) / 2;
    size_t binned_off = thist_off + thist_ints;
    unsigned* binned = (unsigned*)(ib + binned_off);
    size_t csr_off = (binned_off + (size_t)E + 3) & ~(size_t)3;       // 16B-align
    int*   csr   = ib + csr_off;

    (void)hipMemsetAsync(bcnt, 0, NB * sizeof(int), stream);

    const int B = 256;
    k_coarse<<<ntiles, B, 0, stream>>>(dst, E, bcnt, thist);
    k_scan<<<1, B, 0, stream>>>(bcnt, bptr, gcur);
    k_bin<<<ntiles, 512, 0, stream>>>(src, dst, E, gcur, thist, binned);
    k_csr<<<NB, 512, 0, stream>>>(bptr, binned, dis, rowptr, plen4, csr, n);
    k_xw1<<<(n + 1 + B - 1) / B, B, 0, stream>>>(x, W1, dis, featp, n);
    k_gather<1><<<((n + 1) * 4 + B - 1) / B, B, 0, stream>>>(rowptr, plen4, csr, dis, featp,
                                                             nullptr, b1, (void*)h1p, n);
    k_gather<2><<<((n + 1) * 4 + B - 1) / B, B, 0, stream>>>(rowptr, plen4, csr, dis, h1p,
                                                             W2, b2, d_out, n);
}

// Round 10
// 246.687 us; speedup vs baseline: 3.5381x; 1.1269x over previous
//
#include <hip/hip_runtime.h>
#include <hip/hip_fp16.h>

// QNetGNN: 2-layer GCN, N=100000, E=3.2M, F: 128 -> 16 -> 32.
// R10 (= R9 + k_scan fix: 512 threads, NB=392 > 256 caused OOB poison reads).
// Staged-LDS coalesced k_bin, 256-node buckets, fp16 feature tables
// (L2-resident), fp32 accumulation. featp = h*dis pre-scaled; self loop =
// own row; dummy row n = zeros for CSR padding.

#define NNODES 100000
#define FIN    128
#define FHID   16
#define NACT   32
#define NB     392          // ceil(100000/256) buckets of 256 dst nodes
#define BSH    8            // bucket shift (256 nodes/bucket)
#define BMSK   255
#define TILE   4096
#define PADHEAD 1024        // per-bucket csr padding headroom (256*3 + align)

// ---- coarse histogram of dst buckets; also store per-tile hist (ushort) ----
__global__ void k_coarse(const int* __restrict__ dst, int E, int* __restrict__ bcnt,
                         unsigned short* __restrict__ thist) {
    __shared__ int hist[NB];
    int t = threadIdx.x;
    int tb = blockIdx.x * TILE;
    int tn = min(TILE, E - tb);
    for (int i = t; i < NB; i += 256) hist[i] = 0;
    __syncthreads();
    for (int i = t; i < tn; i += 256) atomicAdd(&hist[dst[tb + i] >> BSH], 1);
    __syncthreads();
    size_t row = (size_t)blockIdx.x * NB;
    for (int i = t; i < NB; i += 256) {
        int hv = hist[i];
        thist[row + i] = (unsigned short)hv;
        if (hv) atomicAdd(&bcnt[i], hv);
    }
}

// ---- exclusive scan of bcnt -> bptr[0..NB], init gcur (512 thr, NB<=512) ----
__global__ void __launch_bounds__(512) k_scan(
        const int* __restrict__ bcnt, int* __restrict__ bptr,
        int* __restrict__ gcur) {
    __shared__ int part[512];
    int t = threadIdx.x;
    int c = (t < NB) ? bcnt[t] : 0;
    part[t] = c;
    __syncthreads();
    for (int d = 1; d < 512; d <<= 1) {
        int v = part[t];
        int add = (t >= d) ? part[t - d] : 0;
        __syncthreads();
        part[t] = v + add;
        __syncthreads();
    }
    int excl = t ? part[t - 1] : 0;
    if (t < NB) { bptr[t] = excl; gcur[t] = excl; }
    if (t == NB) bptr[NB] = excl;      // total (c==0 for t>=NB)
}

// ---- bin: staged LDS counting sort, precomputed global dests, 512 thr ----
__global__ void __launch_bounds__(512) k_bin(
        const int* __restrict__ src, const int* __restrict__ dst, int E,
        int* __restrict__ gcur, const unsigned short* __restrict__ thist,
        unsigned* __restrict__ binned) {
    __shared__ unsigned staged[TILE];     // 16 KB
    __shared__ int gscat[TILE];           // 16 KB
    __shared__ int lstart[NB + 1];
    __shared__ int lcur[NB];
    __shared__ int gbase[NB];
    __shared__ int part[512];
    int t = threadIdx.x;
    int tb = blockIdx.x * TILE;
    int tn = min(TILE, E - tb);
    size_t row = (size_t)blockIdx.x * NB;
    int c = (t < NB) ? (int)thist[row + t] : 0;
    part[t] = c;
    __syncthreads();
    for (int d = 1; d < 512; d <<= 1) {
        int v = part[t];
        int add = (t >= d) ? part[t - d] : 0;
        __syncthreads();
        part[t] = v + add;
        __syncthreads();
    }
    int excl = t ? part[t - 1] : 0;
    if (t < NB) { lstart[t] = excl; lcur[t] = excl; }
    if (t == NB) lstart[NB] = excl;
    __syncthreads();
    // reserve global runs (one atomic per non-empty bucket per tile)
    if (t < NB) gbase[t] = (c > 0) ? atomicAdd(&gcur[t], c) : 0;
    __syncthreads();
    // local scatter: value + final global destination
    for (int i = t; i < tn; i += 512) {
        int d = dst[tb + i], sv = src[tb + i];
        int b = d >> BSH;
        int pos = atomicAdd(&lcur[b], 1);
        staged[pos] = ((unsigned)sv << BSH) | (unsigned)(d & BMSK);
        gscat[pos] = gbase[b] + (pos - lstart[b]);
    }
    __syncthreads();
    // write-out: coalesced LDS reads; global writes coalesced within runs
    for (int j = t; j < tn; j += 512) binned[gscat[j]] = staged[j];
}

// ---- per-bucket (256 nodes): degrees -> dis; padded CSR (entries src*4) ----
__global__ void __launch_bounds__(512) k_csr(
        const int* __restrict__ bptr, const unsigned* __restrict__ binned,
        float* __restrict__ dis, int* __restrict__ rowptr,
        int* __restrict__ plen4, int* __restrict__ csr, int n) {
    __shared__ int cnt[256];
    __shared__ int pl[256];
    __shared__ int part[256];
    __shared__ int lbase[256];
    __shared__ int lcur[256];
    int t = threadIdx.x;
    int bk = blockIdx.x;
    int beg = bptr[bk], end = bptr[bk + 1];
    int rbase = (beg & ~3) + PADHEAD * bk;   // 16B-aligned, padding headroom
    if (t < 256) cnt[t] = 0;
    __syncthreads();
    for (int i = beg + t; i < end; i += 512) atomicAdd(&cnt[binned[i] & BMSK], 1);
    __syncthreads();
    if (t < 256) { pl[t] = (cnt[t] + 3) & ~3; part[t] = pl[t]; }
    __syncthreads();
    for (int d = 1; d < 256; d <<= 1) {
        int v = 0;
        if (t < 256) { v = part[t]; if (t >= d) v += part[t - d]; }
        __syncthreads();
        if (t < 256) part[t] = v;
        __syncthreads();
    }
    if (t < 256) {
        lbase[t] = t ? part[t - 1] : 0;
        lcur[t] = 0;
        int node = (bk << BSH) + t;
        if (node < n) {
            int rp = rbase + lbase[t];
            rowptr[node] = rp;
            plen4[node] = pl[t] >> 2;
            dis[node] = rsqrtf((float)cnt[t] + 1.0f);
            for (int k = cnt[t]; k < pl[t]; ++k) csr[rp + k] = n << 2;  // dummy pad
        }
    }
    __syncthreads();
    for (int i = beg + t; i < end; i += 512) {
        unsigned e = binned[i];
        int dloc = e & BMSK;
        int pos = atomicAdd(&lcur[dloc], 1);
        csr[rbase + lbase[dloc] + pos] = (int)(e >> BSH) << 2;   // pre-shifted
    }
}

#define FMA4(A, S, W) { (A).x += (S) * (W).x; (A).y += (S) * (W).y; \
                        (A).z += (S) * (W).z; (A).w += (S) * (W).w; }

__device__ __forceinline__ unsigned pack2(float a, float b) {
    __half2 h = __floats2half2_rn(a, b);
    return *reinterpret_cast<unsigned*>(&h);
}

// ---- featp = fp16((x @ W1) * dis); row n = zeros ----
__global__ void k_xw1(const float* __restrict__ x, const float* __restrict__ W1,
                      const float* __restrict__ dis, __half* __restrict__ featp, int n) {
    __shared__ float w[FIN * FHID];   // 8 KB, row-major [128][16]
    for (int i = threadIdx.x; i < FIN * FHID; i += blockDim.x) w[i] = W1[i];
    __syncthreads();
    int r = blockIdx.x * blockDim.x + threadIdx.x;
    if (r > n) return;
    uint4* hr = (uint4*)(featp + (size_t)r * FHID);   // 32 B row = 2 uint4
    if (r == n) {
        uint4 z = make_uint4(0u, 0u, 0u, 0u);
        hr[0] = z; hr[1] = z;
        return;
    }
    const float4* xr = (const float4*)(x + (long long)r * FIN);
    const float4* w4 = (const float4*)w;      // [128][4] float4s
    float4 a0 = make_float4(0.f, 0.f, 0.f, 0.f), a1 = a0, a2 = a0, a3 = a0;
#pragma unroll 8
    for (int k4 = 0; k4 < FIN / 4; ++k4) {
        float4 xv = xr[k4];
        int kb = k4 * 16;
        FMA4(a0, xv.x, w4[kb + 0]);  FMA4(a1, xv.x, w4[kb + 1]);
        FMA4(a2, xv.x, w4[kb + 2]);  FMA4(a3, xv.x, w4[kb + 3]);
        FMA4(a0, xv.y, w4[kb + 4]);  FMA4(a1, xv.y, w4[kb + 5]);
        FMA4(a2, xv.y, w4[kb + 6]);  FMA4(a3, xv.y, w4[kb + 7]);
        FMA4(a0, xv.z, w4[kb + 8]);  FMA4(a1, xv.z, w4[kb + 9]);
        FMA4(a2, xv.z, w4[kb + 10]); FMA4(a3, xv.z, w4[kb + 11]);
        FMA4(a0, xv.w, w4[kb + 12]); FMA4(a1, xv.w, w4[kb + 13]);
        FMA4(a2, xv.w, w4[kb + 14]); FMA4(a3, xv.w, w4[kb + 15]);
    }
    float d = dis[r];
    uint4 w0, w1;
    w0.x = pack2(a0.x * d, a0.y * d); w0.y = pack2(a0.z * d, a0.w * d);
    w0.z = pack2(a1.x * d, a1.y * d); w0.w = pack2(a1.z * d, a1.w * d);
    w1.x = pack2(a2.x * d, a2.y * d); w1.y = pack2(a2.z * d, a2.w * d);
    w1.z = pack2(a3.x * d, a3.y * d); w1.w = pack2(a3.z * d, a3.w * d);
    hr[0] = w0; hr[1] = w1;
}

#define ACC8(U) { \
    __half2 h0_ = *reinterpret_cast<__half2*>(&(U).x); \
    __half2 h1_ = *reinterpret_cast<__half2*>(&(U).y); \
    float2 f0_ = __half22float2(h0_); \
    float2 f1_ = __half22float2(h1_); \
    a.x += f0_.x; a.y += f0_.y; a.z += f1_.x; a.w += f1_.y; }

// ---- gather: 4 lanes/node, fp16 rows (8 B/lane), unroll x4 ----
template <int L>
__global__ void __launch_bounds__(256, 6) k_gather(
        const int* __restrict__ rowptr, const int* __restrict__ plen4,
        const int* __restrict__ csr, const float* __restrict__ dis,
        const __half* __restrict__ featp, const float* __restrict__ W2,
        const float* __restrict__ bias, void* __restrict__ outp, int n) {
    __shared__ float wb[FHID * NACT];
    __shared__ float bs[NACT];
    if (L == 2) {
        for (int i = threadIdx.x; i < FHID * NACT; i += 256) wb[i] = W2[i];
        if (threadIdx.x < NACT) bs[threadIdx.x] = bias[threadIdx.x];
        __syncthreads();
    }
    int t = blockIdx.x * blockDim.x + threadIdx.x;
    int node = t >> 2, p = t & 3;
    if (node > n) return;
    const uint2* fp = (const uint2*)featp;    // 4 granules of 8 B per row
    if (node == n) {
        if (L == 1) ((uint2*)outp)[(size_t)node * 4 + p] = make_uint2(0u, 0u);
        return;
    }
    float4 a = make_float4(0.f, 0.f, 0.f, 0.f);
    {   // self loop (pre-scaled)
        uint2 u = fp[(size_t)(node << 2) + p];
        ACC8(u);
    }
    int beg = rowptr[node];
    int it = plen4[node];
    const int4* cp = (const int4*)(csr + beg);
    int k = 0;
    for (; k + 4 <= it; k += 4) {
        int4 s0 = cp[k], s1 = cp[k + 1], s2 = cp[k + 2], s3 = cp[k + 3];
        uint2 u0 = fp[(size_t)s0.x + p];
        uint2 u1 = fp[(size_t)s0.y + p];
        uint2 u2 = fp[(size_t)s0.z + p];
        uint2 u3 = fp[(size_t)s0.w + p];
        uint2 u4 = fp[(size_t)s1.x + p];
        uint2 u5 = fp[(size_t)s1.y + p];
        uint2 u6 = fp[(size_t)s1.z + p];
        uint2 u7 = fp[(size_t)s1.w + p];
        uint2 u8 = fp[(size_t)s2.x + p];
        uint2 u9 = fp[(size_t)s2.y + p];
        uint2 ua = fp[(size_t)s2.z + p];
        uint2 ub = fp[(size_t)s2.w + p];
        uint2 uc = fp[(size_t)s3.x + p];
        uint2 ud = fp[(size_t)s3.y + p];
        uint2 ue = fp[(size_t)s3.z + p];
        uint2 uf = fp[(size_t)s3.w + p];
        ACC8(u0); ACC8(u1); ACC8(u2); ACC8(u3);
        ACC8(u4); ACC8(u5); ACC8(u6); ACC8(u7);
        ACC8(u8); ACC8(u9); ACC8(ua); ACC8(ub);
        ACC8(uc); ACC8(ud); ACC8(ue); ACC8(uf);
    }
    for (; k < it; ++k) {
        int4 s4 = cp[k];
        uint2 u0 = fp[(size_t)s4.x + p];
        uint2 u1 = fp[(size_t)s4.y + p];
        uint2 u2 = fp[(size_t)s4.z + p];
        uint2 u3 = fp[(size_t)s4.w + p];
        ACC8(u0); ACC8(u1); ACC8(u2); ACC8(u3);
    }
    float di = dis[node];
    if (L == 1) {
        float4 bv = ((const float4*)bias)[p];
        float rx = fmaxf(di * a.x + bv.x, 0.f) * di;   // pre-scaled for layer 2
        float ry = fmaxf(di * a.y + bv.y, 0.f) * di;
        float rz = fmaxf(di * a.z + bv.z, 0.f) * di;
        float rw = fmaxf(di * a.w + bv.w, 0.f) * di;
        uint2 w;
        w.x = pack2(rx, ry);
        w.y = pack2(rz, rw);
        ((uint2*)outp)[(size_t)node * 4 + p] = w;
    } else {
        float4 pa = make_float4(di * a.x, di * a.y, di * a.z, di * a.w);
        int base4 = (threadIdx.x & 63) & ~3;
        float p16[16];
#pragma unroll
        for (int q = 0; q < 4; ++q) {
            p16[q * 4 + 0] = __shfl(pa.x, base4 + q, 64);
            p16[q * 4 + 1] = __shfl(pa.y, base4 + q, 64);
            p16[q * 4 + 2] = __shfl(pa.z, base4 + q, 64);
            p16[q * 4 + 3] = __shfl(pa.w, base4 + q, 64);
        }
        float o[8];
#pragma unroll
        for (int j = 0; j < 8; ++j) {
            int col = p * 8 + j;
            float acc = bs[col];
#pragma unroll
            for (int c = 0; c < FHID; ++c) acc += p16[c] * wb[c * NACT + col];
            o[j] = acc;
        }
        ((float4*)outp)[(size_t)node * 8 + p * 2 + 0] = make_float4(o[0], o[1], o[2], o[3]);
        ((float4*)outp)[(size_t)node * 8 + p * 2 + 1] = make_float4(o[4], o[5], o[6], o[7]);
    }
}

extern "C" void kernel_launch(void* const* d_in, const int* in_sizes, int n_in,
                              void* d_out, int out_size, void* d_ws, size_t ws_size,
                              hipStream_t stream) {
    const float* x  = (const float*)d_in[0];
    const float* W1 = (const float*)d_in[1];
    const float* b1 = (const float*)d_in[2];
    const float* W2 = (const float*)d_in[3];
    const float* b2 = (const float*)d_in[4];
    const int*   ei = (const int*)d_in[5];
    const int E = in_sizes[5] / 2;
    const int n = NNODES;
    const int npad = n + 8;               // keeps fp16 tables 16B-aligned
    const int* src = ei;
    const int* dst = ei + E;
    const int ntiles = (E + TILE - 1) / TILE;

    // floats: dis[n] | featp fp16 [16*npad] | h1p fp16 [16*npad]
    // ints:   bcnt[NB] bptr[NB+1] gcur[NB] rowptr[n] plen4[n]
    //         | thist[ntiles*NB] ushort | binned[E] | csr[E+PADHEAD*NB+64]
    float* fb    = (float*)d_ws;
    float* dis   = fb;
    __half* featp = (__half*)(fb + (size_t)n);
    __half* h1p   = featp + (size_t)16 * npad;
    int*   ib    = (int*)(h1p + (size_t)16 * npad);
    int*   bcnt  = ib;
    int*   bptr  = ib + NB;
    int*   gcur  = ib + 2 * NB + 1;
    int*   rowptr = ib + 3 * NB + 1;
    int*   plen4 = rowptr + n;
    size_t thist_off = (size_t)(3 * NB + 1) + 2 * (size_t)n;          // in ints
    unsigned short* thist = (unsigned short*)(ib + thist_off);
    size_t thist_ints = ((size_t)ntiles * NB + 1) / 2;
    size_t binned_off = thist_off + thist_ints;
    unsigned* binned = (unsigned*)(ib + binned_off);
    size_t csr_off = (binned_off + (size_t)E + 3) & ~(size_t)3;       // 16B-align
    int*   csr   = ib + csr_off;

    (void)hipMemsetAsync(bcnt, 0, NB * sizeof(int), stream);

    const int B = 256;
    k_coarse<<<ntiles, B, 0, stream>>>(dst, E, bcnt, thist);
    k_scan<<<1, 512, 0, stream>>>(bcnt, bptr, gcur);
    k_bin<<<ntiles, 512, 0, stream>>>(src, dst, E, gcur, thist, binned);
    k_csr<<<NB, 512, 0, stream>>>(bptr, binned, dis, rowptr, plen4, csr, n);
    k_xw1<<<(n + 1 + B - 1) / B, B, 0, stream>>>(x, W1, dis, featp, n);
    k_gather<1><<<((n + 1) * 4 + B - 1) / B, B, 0, stream>>>(rowptr, plen4, csr, dis, featp,
                                                             nullptr, b1, (void*)h1p, n);
    k_gather<2><<<((n + 1) * 4 + B - 1) / B, B, 0, stream>>>(rowptr, plen4, csr, dis, h1p,
                                                             W2, b2, d_out, n);
}

// Round 11
// 239.844 us; speedup vs baseline: 3.6390x; 1.0285x over previous
//
#include <hip/hip_runtime.h>
#include <hip/hip_fp16.h>

// QNetGNN: 2-layer GCN, N=100000, E=3.2M, F: 128 -> 16 -> 32.
// R11: gathers at 8 lanes/node (two quads split the edge list, __shfl_xor(4)
// reduce -> 2x waves in flight for the latency-bound random row reads);
// k_csr at 1024 thr/block (grid fixed at NB=392 -> taller blocks = more
// waves). Staged-LDS k_bin, 256-node buckets, fp16 feature tables
// (L2-resident), fp32 accumulation. featp = h*dis pre-scaled; self loop =
// own row; dummy row n = zeros for CSR padding.

#define NNODES 100000
#define FIN    128
#define FHID   16
#define NACT   32
#define NB     392          // ceil(100000/256) buckets of 256 dst nodes
#define BSH    8            // bucket shift (256 nodes/bucket)
#define BMSK   255
#define TILE   4096
#define PADHEAD 1024        // per-bucket csr padding headroom

// ---- coarse histogram of dst buckets; also store per-tile hist (ushort) ----
__global__ void k_coarse(const int* __restrict__ dst, int E, int* __restrict__ bcnt,
                         unsigned short* __restrict__ thist) {
    __shared__ int hist[NB];
    int t = threadIdx.x;
    int tb = blockIdx.x * TILE;
    int tn = min(TILE, E - tb);
    for (int i = t; i < NB; i += 256) hist[i] = 0;
    __syncthreads();
    for (int i = t; i < tn; i += 256) atomicAdd(&hist[dst[tb + i] >> BSH], 1);
    __syncthreads();
    size_t row = (size_t)blockIdx.x * NB;
    for (int i = t; i < NB; i += 256) {
        int hv = hist[i];
        thist[row + i] = (unsigned short)hv;
        if (hv) atomicAdd(&bcnt[i], hv);
    }
}

// ---- exclusive scan of bcnt -> bptr[0..NB], init gcur (512 thr, NB<=512) ----
__global__ void __launch_bounds__(512) k_scan(
        const int* __restrict__ bcnt, int* __restrict__ bptr,
        int* __restrict__ gcur) {
    __shared__ int part[512];
    int t = threadIdx.x;
    int c = (t < NB) ? bcnt[t] : 0;
    part[t] = c;
    __syncthreads();
    for (int d = 1; d < 512; d <<= 1) {
        int v = part[t];
        int add = (t >= d) ? part[t - d] : 0;
        __syncthreads();
        part[t] = v + add;
        __syncthreads();
    }
    int excl = t ? part[t - 1] : 0;
    if (t < NB) { bptr[t] = excl; gcur[t] = excl; }
    if (t == NB) bptr[NB] = excl;      // total (c==0 for t>=NB)
}

// ---- bin: staged LDS counting sort, precomputed global dests, 512 thr ----
__global__ void __launch_bounds__(512) k_bin(
        const int* __restrict__ src, const int* __restrict__ dst, int E,
        int* __restrict__ gcur, const unsigned short* __restrict__ thist,
        unsigned* __restrict__ binned) {
    __shared__ unsigned staged[TILE];     // 16 KB
    __shared__ int gscat[TILE];           // 16 KB
    __shared__ int lstart[NB + 1];
    __shared__ int lcur[NB];
    __shared__ int gbase[NB];
    __shared__ int part[512];
    int t = threadIdx.x;
    int tb = blockIdx.x * TILE;
    int tn = min(TILE, E - tb);
    size_t row = (size_t)blockIdx.x * NB;
    int c = (t < NB) ? (int)thist[row + t] : 0;
    part[t] = c;
    __syncthreads();
    for (int d = 1; d < 512; d <<= 1) {
        int v = part[t];
        int add = (t >= d) ? part[t - d] : 0;
        __syncthreads();
        part[t] = v + add;
        __syncthreads();
    }
    int excl = t ? part[t - 1] : 0;
    if (t < NB) { lstart[t] = excl; lcur[t] = excl; }
    if (t == NB) lstart[NB] = excl;
    __syncthreads();
    if (t < NB) gbase[t] = (c > 0) ? atomicAdd(&gcur[t], c) : 0;
    __syncthreads();
    for (int i = t; i < tn; i += 512) {
        int d = dst[tb + i], sv = src[tb + i];
        int b = d >> BSH;
        int pos = atomicAdd(&lcur[b], 1);
        staged[pos] = ((unsigned)sv << BSH) | (unsigned)(d & BMSK);
        gscat[pos] = gbase[b] + (pos - lstart[b]);
    }
    __syncthreads();
    for (int j = t; j < tn; j += 512) binned[gscat[j]] = staged[j];
}

// ---- per-bucket (256 nodes): degrees -> dis; padded CSR (entries src*4) ----
// 1024 threads: grid is fixed at NB blocks, taller blocks add waves.
__global__ void __launch_bounds__(1024) k_csr(
        const int* __restrict__ bptr, const unsigned* __restrict__ binned,
        float* __restrict__ dis, int* __restrict__ rowptr,
        int* __restrict__ plen4, int* __restrict__ csr, int n) {
    __shared__ int cnt[256];
    __shared__ int pl[256];
    __shared__ int part[256];
    __shared__ int lbase[256];
    __shared__ int lcur[256];
    int t = threadIdx.x;
    int bk = blockIdx.x;
    int beg = bptr[bk], end = bptr[bk + 1];
    int rbase = (beg & ~3) + PADHEAD * bk;   // 16B-aligned, padding headroom
    if (t < 256) cnt[t] = 0;
    __syncthreads();
    for (int i = beg + t; i < end; i += 1024) atomicAdd(&cnt[binned[i] & BMSK], 1);
    __syncthreads();
    if (t < 256) { pl[t] = (cnt[t] + 3) & ~3; part[t] = pl[t]; }
    __syncthreads();
    for (int d = 1; d < 256; d <<= 1) {
        int v = 0;
        if (t < 256) { v = part[t]; if (t >= d) v += part[t - d]; }
        __syncthreads();
        if (t < 256) part[t] = v;
        __syncthreads();
    }
    if (t < 256) {
        lbase[t] = t ? part[t - 1] : 0;
        lcur[t] = 0;
        int node = (bk << BSH) + t;
        if (node < n) {
            int rp = rbase + lbase[t];
            rowptr[node] = rp;
            plen4[node] = pl[t] >> 2;
            dis[node] = rsqrtf((float)cnt[t] + 1.0f);
            for (int k = cnt[t]; k < pl[t]; ++k) csr[rp + k] = n << 2;  // dummy pad
        }
    }
    __syncthreads();
    for (int i = beg + t; i < end; i += 1024) {
        unsigned e = binned[i];
        int dloc = e & BMSK;
        int pos = atomicAdd(&lcur[dloc], 1);
        csr[rbase + lbase[dloc] + pos] = (int)(e >> BSH) << 2;   // pre-shifted
    }
}

#define FMA4(A, S, W) { (A).x += (S) * (W).x; (A).y += (S) * (W).y; \
                        (A).z += (S) * (W).z; (A).w += (S) * (W).w; }

__device__ __forceinline__ unsigned pack2(float a, float b) {
    __half2 h = __floats2half2_rn(a, b);
    return *reinterpret_cast<unsigned*>(&h);
}

// ---- featp = fp16((x @ W1) * dis); row n = zeros ----
__global__ void k_xw1(const float* __restrict__ x, const float* __restrict__ W1,
                      const float* __restrict__ dis, __half* __restrict__ featp, int n) {
    __shared__ float w[FIN * FHID];   // 8 KB, row-major [128][16]
    for (int i = threadIdx.x; i < FIN * FHID; i += blockDim.x) w[i] = W1[i];
    __syncthreads();
    int r = blockIdx.x * blockDim.x + threadIdx.x;
    if (r > n) return;
    uint4* hr = (uint4*)(featp + (size_t)r * FHID);   // 32 B row = 2 uint4
    if (r == n) {
        uint4 z = make_uint4(0u, 0u, 0u, 0u);
        hr[0] = z; hr[1] = z;
        return;
    }
    const float4* xr = (const float4*)(x + (long long)r * FIN);
    const float4* w4 = (const float4*)w;      // [128][4] float4s
    float4 a0 = make_float4(0.f, 0.f, 0.f, 0.f), a1 = a0, a2 = a0, a3 = a0;
#pragma unroll 8
    for (int k4 = 0; k4 < FIN / 4; ++k4) {
        float4 xv = xr[k4];
        int kb = k4 * 16;
        FMA4(a0, xv.x, w4[kb + 0]);  FMA4(a1, xv.x, w4[kb + 1]);
        FMA4(a2, xv.x, w4[kb + 2]);  FMA4(a3, xv.x, w4[kb + 3]);
        FMA4(a0, xv.y, w4[kb + 4]);  FMA4(a1, xv.y, w4[kb + 5]);
        FMA4(a2, xv.y, w4[kb + 6]);  FMA4(a3, xv.y, w4[kb + 7]);
        FMA4(a0, xv.z, w4[kb + 8]);  FMA4(a1, xv.z, w4[kb + 9]);
        FMA4(a2, xv.z, w4[kb + 10]); FMA4(a3, xv.z, w4[kb + 11]);
        FMA4(a0, xv.w, w4[kb + 12]); FMA4(a1, xv.w, w4[kb + 13]);
        FMA4(a2, xv.w, w4[kb + 14]); FMA4(a3, xv.w, w4[kb + 15]);
    }
    float d = dis[r];
    uint4 w0, w1;
    w0.x = pack2(a0.x * d, a0.y * d); w0.y = pack2(a0.z * d, a0.w * d);
    w0.z = pack2(a1.x * d, a1.y * d); w0.w = pack2(a1.z * d, a1.w * d);
    w1.x = pack2(a2.x * d, a2.y * d); w1.y = pack2(a2.z * d, a2.w * d);
    w1.z = pack2(a3.x * d, a3.y * d); w1.w = pack2(a3.z * d, a3.w * d);
    hr[0] = w0; hr[1] = w1;
}

#define ACC8(U) { \
    __half2 h0_ = *reinterpret_cast<__half2*>(&(U).x); \
    __half2 h1_ = *reinterpret_cast<__half2*>(&(U).y); \
    float2 f0_ = __half22float2(h0_); \
    float2 f1_ = __half22float2(h1_); \
    a.x += f0_.x; a.y += f0_.y; a.z += f1_.x; a.w += f1_.y; }

// ---- gather: 8 lanes/node (2 quads split edges), fp16 rows, shfl reduce ----
// L==1: h1p = fp16(relu(di*sum + b1)*di)   [N,16]
// L==2: out = (di*sum) @ W2 + b2           [N,32] fp32 (W2 fused)
template <int L>
__global__ void __launch_bounds__(256, 6) k_gather(
        const int* __restrict__ rowptr, const int* __restrict__ plen4,
        const int* __restrict__ csr, const float* __restrict__ dis,
        const __half* __restrict__ featp, const float* __restrict__ W2,
        const float* __restrict__ bias, void* __restrict__ outp, int n) {
    __shared__ float wb[FHID * NACT];
    __shared__ float bs[NACT];
    if (L == 2) {
        for (int i = threadIdx.x; i < FHID * NACT; i += 256) wb[i] = W2[i];
        if (threadIdx.x < NACT) bs[threadIdx.x] = bias[threadIdx.x];
        __syncthreads();
    }
    int t = blockIdx.x * blockDim.x + threadIdx.x;
    int node = t >> 3, p8 = t & 7, p = p8 & 3, half = p8 >> 2;
    if (node > n) return;
    const uint2* fp = (const uint2*)featp;    // 4 granules of 8 B per row
    if (node == n) {
        if (L == 1 && half == 0) ((uint2*)outp)[(size_t)node * 4 + p] = make_uint2(0u, 0u);
        return;
    }
    float4 a = make_float4(0.f, 0.f, 0.f, 0.f);
    if (half == 0) {   // self loop (pre-scaled)
        uint2 u = fp[(size_t)(node << 2) + p];
        ACC8(u);
    }
    int beg = rowptr[node];
    int it = plen4[node];
    const int4* cp = (const int4*)(csr + beg);
    int k = half;                 // int4 groups k === half (mod 2)
    for (; k + 3 <= it; k += 4) {  // 2 groups: k, k+2 -> 8 loads in flight
        int4 s0 = cp[k], s1 = cp[k + 2];
        uint2 u0 = fp[(size_t)s0.x + p];
        uint2 u1 = fp[(size_t)s0.y + p];
        uint2 u2 = fp[(size_t)s0.z + p];
        uint2 u3 = fp[(size_t)s0.w + p];
        uint2 u4 = fp[(size_t)s1.x + p];
        uint2 u5 = fp[(size_t)s1.y + p];
        uint2 u6 = fp[(size_t)s1.z + p];
        uint2 u7 = fp[(size_t)s1.w + p];
        ACC8(u0); ACC8(u1); ACC8(u2); ACC8(u3);
        ACC8(u4); ACC8(u5); ACC8(u6); ACC8(u7);
    }
    if (k < it) {
        int4 s0 = cp[k];
        uint2 u0 = fp[(size_t)s0.x + p];
        uint2 u1 = fp[(size_t)s0.y + p];
        uint2 u2 = fp[(size_t)s0.z + p];
        uint2 u3 = fp[(size_t)s0.w + p];
        ACC8(u0); ACC8(u1); ACC8(u2); ACC8(u3);
    }
    // combine the two halves (lane ^ 4 within the 8-lane group)
    a.x += __shfl_xor(a.x, 4, 64);
    a.y += __shfl_xor(a.y, 4, 64);
    a.z += __shfl_xor(a.z, 4, 64);
    a.w += __shfl_xor(a.w, 4, 64);
    float di = dis[node];
    if (L == 1) {
        if (half == 0) {
            float4 bv = ((const float4*)bias)[p];
            float rx = fmaxf(di * a.x + bv.x, 0.f) * di;   // pre-scaled for layer 2
            float ry = fmaxf(di * a.y + bv.y, 0.f) * di;
            float rz = fmaxf(di * a.z + bv.z, 0.f) * di;
            float rw = fmaxf(di * a.w + bv.w, 0.f) * di;
            uint2 w;
            w.x = pack2(rx, ry);
            w.y = pack2(rz, rw);
            ((uint2*)outp)[(size_t)node * 4 + p] = w;
        }
    } else {
        float4 pa = make_float4(di * a.x, di * a.y, di * a.z, di * a.w);
        int base8 = (threadIdx.x & 63) & ~7;
        float p16[16];
#pragma unroll
        for (int q = 0; q < 4; ++q) {
            p16[q * 4 + 0] = __shfl(pa.x, base8 + q, 64);
            p16[q * 4 + 1] = __shfl(pa.y, base8 + q, 64);
            p16[q * 4 + 2] = __shfl(pa.z, base8 + q, 64);
            p16[q * 4 + 3] = __shfl(pa.w, base8 + q, 64);
        }
        float o[4];
#pragma unroll
        for (int j = 0; j < 4; ++j) {
            int col = p8 * 4 + j;
            float acc = bs[col];
#pragma unroll
            for (int c = 0; c < FHID; ++c) acc += p16[c] * wb[c * NACT + col];
            o[j] = acc;
        }
        ((float4*)outp)[(size_t)node * 8 + p8] = make_float4(o[0], o[1], o[2], o[3]);
    }
}

extern "C" void kernel_launch(void* const* d_in, const int* in_sizes, int n_in,
                              void* d_out, int out_size, void* d_ws, size_t ws_size,
                              hipStream_t stream) {
    const float* x  = (const float*)d_in[0];
    const float* W1 = (const float*)d_in[1];
    const float* b1 = (const float*)d_in[2];
    const float* W2 = (const float*)d_in[3];
    const float* b2 = (const float*)d_in[4];
    const int*   ei = (const int*)d_in[5];
    const int E = in_sizes[5] / 2;
    const int n = NNODES;
    const int npad = n + 8;               // keeps fp16 tables 16B-aligned
    const int* src = ei;
    const int* dst = ei + E;
    const int ntiles = (E + TILE - 1) / TILE;

    // floats: dis[n] | featp fp16 [16*npad] | h1p fp16 [16*npad]
    // ints:   bcnt[NB] bptr[NB+1] gcur[NB] rowptr[n] plen4[n]
    //         | thist[ntiles*NB] ushort | binned[E] | csr[E+PADHEAD*NB+64]
    float* fb    = (float*)d_ws;
    float* dis   = fb;
    __half* featp = (__half*)(fb + (size_t)n);
    __half* h1p   = featp + (size_t)16 * npad;
    int*   ib    = (int*)(h1p + (size_t)16 * npad);
    int*   bcnt  = ib;
    int*   bptr  = ib + NB;
    int*   gcur  = ib + 2 * NB + 1;
    int*   rowptr = ib + 3 * NB + 1;
    int*   plen4 = rowptr + n;
    size_t thist_off = (size_t)(3 * NB + 1) + 2 * (size_t)n;          // in ints
    unsigned short* thist = (unsigned short*)(ib + thist_off);
    size_t thist_ints = ((size_t)ntiles * NB + 1) / 2;
    size_t binned_off = thist_off + thist_ints;
    unsigned* binned = (unsigned*)(ib + binned_off);
    size_t csr_off = (binned_off + (size_t)E + 3) & ~(size_t)3;       // 16B-align
    int*   csr   = ib + csr_off;

    (void)hipMemsetAsync(bcnt, 0, NB * sizeof(int), stream);

    const int B = 256;
    k_coarse<<<ntiles, B, 0, stream>>>(dst, E, bcnt, thist);
    k_scan<<<1, 512, 0, stream>>>(bcnt, bptr, gcur);
    k_bin<<<ntiles, 512, 0, stream>>>(src, dst, E, gcur, thist, binned);
    k_csr<<<NB, 1024, 0, stream>>>(bptr, binned, dis, rowptr, plen4, csr, n);
    k_xw1<<<(n + 1 + B - 1) / B, B, 0, stream>>>(x, W1, dis, featp, n);
    k_gather<1><<<((n + 1) * 8 + B - 1) / B, B, 0, stream>>>(rowptr, plen4, csr, dis, featp,
                                                             nullptr, b1, (void*)h1p, n);
    k_gather<2><<<((n + 1) * 8 + B - 1) / B, B, 0, stream>>>(rowptr, plen4, csr, dis, h1p,
                                                             W2, b2, d_out, n);
}